// Round 7
// baseline (349.457 us; speedup 1.0000x reference)
//
#include <hip/hip_runtime.h>
#include <hip/hip_bf16.h>

#define N_NODES 20000
#define M_PAD 20096            // 314 * 64
#define IN_DIM 128
#define HID 256
#define OUT_DIM 10
#define N_EDGES 320000
#define N_GRAPHS 64

typedef __attribute__((ext_vector_type(8))) short bf16x8;
typedef __attribute__((ext_vector_type(4))) float f32x4;

__device__ inline float bf2f(unsigned short u) {
    return __uint_as_float((unsigned int)u << 16);
}
__device__ inline unsigned short f2bf(float f) {
    __hip_bfloat16 h = __float2bfloat16(f);
    return *reinterpret_cast<unsigned short*>(&h);
}

__device__ __forceinline__ void gl16(const void* g, void* l) {
    __builtin_amdgcn_global_load_lds(
        (const __attribute__((address_space(1))) unsigned int*)g,
        (__attribute__((address_space(3))) unsigned int*)l, 16, 0, 0);
}

template<int N> __device__ __forceinline__ void vmwait() {
    asm volatile("s_waitcnt vmcnt(%0)" :: "n"(N) : "memory");
    __builtin_amdgcn_sched_barrier(0);
}

__device__ __forceinline__ void bar() {
    __builtin_amdgcn_s_barrier();
    __builtin_amdgcn_sched_barrier(0);
}

// ---------------------------------------------------------------------------
// CSR build
__global__ void degree_hist(const int* __restrict__ dst, int* __restrict__ deg, int n) {
    int i = blockIdx.x * blockDim.x + threadIdx.x;
    int stride = gridDim.x * blockDim.x;
    for (; i < n; i += stride) atomicAdd(&deg[dst[i]], 1);
}

__global__ __launch_bounds__(1024) void scan_deg(const int* __restrict__ deg,
                                                 int* __restrict__ row_ptr,
                                                 int* __restrict__ pos, int n) {
    __shared__ int sums[1024];
    int tid = threadIdx.x;
    int chunk = (n + 1023) / 1024;
    int base = tid * chunk;
    int s = 0;
    for (int i = 0; i < chunk; ++i) {
        int idx = base + i;
        if (idx < n) s += deg[idx];
    }
    sums[tid] = s;
    __syncthreads();
    for (int off = 1; off < 1024; off <<= 1) {
        int v = (tid >= off) ? sums[tid - off] : 0;
        __syncthreads();
        if (tid >= off) sums[tid] += v;
        __syncthreads();
    }
    int run = (tid == 0) ? 0 : sums[tid - 1];
    for (int i = 0; i < chunk; ++i) {
        int idx = base + i;
        if (idx < n) {
            row_ptr[idx] = run;
            pos[idx] = run;
            run += deg[idx];
            if (idx == n - 1) row_ptr[n] = run;
        }
    }
}

__global__ void csr_fill(const int* __restrict__ src, const int* __restrict__ dst,
                         int* __restrict__ pos, int* __restrict__ col, int n) {
    int i = blockIdx.x * blockDim.x + threadIdx.x;
    int stride = gridDim.x * blockDim.x;
    for (; i < n; i += stride) {
        int slot = atomicAdd(&pos[dst[i]], 1);
        col[slot] = src[i];
    }
}

// ---------------------------------------------------------------------------
// batched prep: z<6 weight transpose+convert; z==6 zero pooled/deg; z==7 x->bf16
__global__ __launch_bounds__(256) void transpose_all(
    const float* __restrict__ w1a, const float* __restrict__ w1b,
    const float* __restrict__ w2a, const float* __restrict__ w2b,
    const float* __restrict__ w3a, const float* __restrict__ w3b,
    __hip_bfloat16* __restrict__ o1a, __hip_bfloat16* __restrict__ o1b,
    __hip_bfloat16* __restrict__ o2a, __hip_bfloat16* __restrict__ o2b,
    __hip_bfloat16* __restrict__ o3a, __hip_bfloat16* __restrict__ o3b,
    int* __restrict__ zp, int zn,
    const float* __restrict__ x, __hip_bfloat16* __restrict__ x_bf, int n4)
{
    __shared__ float tile[32][33];
    int z = blockIdx.z;
    if (z == 6) {
        int i = (blockIdx.y * 8 + blockIdx.x) * 256 + threadIdx.x;
        for (; i < zn; i += 64 * 256) zp[i] = 0;
        return;
    }
    if (z == 7) {
        int i = (blockIdx.y * 8 + blockIdx.x) * 256 + threadIdx.x;
        for (; i < n4; i += 64 * 256) {
            float4 v = reinterpret_cast<const float4*>(x)[i];
            ushort4 u;
            u.x = f2bf(v.x); u.y = f2bf(v.y); u.z = f2bf(v.z); u.w = f2bf(v.w);
            reinterpret_cast<ushort4*>(x_bf)[i] = u;
        }
        return;
    }
    const float* in = (z == 0) ? w1a : (z == 1) ? w1b : (z == 2) ? w2a
                    : (z == 3) ? w2b : (z == 4) ? w3a : w3b;
    __hip_bfloat16* out = (z == 0) ? o1a : (z == 1) ? o1b : (z == 2) ? o2a
                        : (z == 3) ? o2b : (z == 4) ? o3a : o3b;
    int rows = (z == 0) ? IN_DIM : HID;
    int r0 = blockIdx.y * 32;
    if (r0 >= rows) return;
    int c0 = blockIdx.x * 32;
    int tx = threadIdx.x & 31, ty = threadIdx.x >> 5;
    for (int i = ty; i < 32; i += 8)
        tile[i][tx] = in[(size_t)(r0 + i) * HID + c0 + tx];
    __syncthreads();
    for (int i = ty; i < 32; i += 8)
        out[(size_t)(c0 + i) * rows + r0 + tx] = __float2bfloat16(tile[tx][i]);
}

// ---------------------------------------------------------------------------
// FUSED layer: gather(A rows) in-block, then C = relu(relu(A@W1t^T+b1)@W2t^T+b2)
// BM=64, BN=256; 4 waves; LDS: AT 32KB (A tile, then mid) + WB 2x16KB = 64KB.
template<int K1>
__global__ __launch_bounds__(256) void gin_mlp(
    const __hip_bfloat16* __restrict__ X,
    const int* __restrict__ row_ptr, const int* __restrict__ col,
    const __hip_bfloat16* __restrict__ W1t, const float* __restrict__ b1,
    const __hip_bfloat16* __restrict__ W2t, const float* __restrict__ b2,
    __hip_bfloat16* __restrict__ C)
{
    __shared__ int4 smem4[4096];       // 65536 B
    char* AT = (char*)smem4;           // 32KB: A tile (swizzled), later mid
    char* WB = AT + 32768;             // 2 x 16KB W staging buffers

    const int tid = threadIdx.x, lane = tid & 63, wid = tid >> 6;
    const int m0 = blockIdx.x * 64;
    const int r16 = lane & 15, g = lane >> 4;
    const int gg = g ^ ((r16 >> 1) & 3);   // W-tile read swizzle (64B rows)

    // staging source addresses (pre-swizzled chunk so linear LDS dest works)
    const int rseg = lane >> 2;
    const int sw = (lane & 3) ^ ((lane >> 3) & 3);
    const char* gW1[4];
    const char* gW2[4];
    #pragma unroll
    for (int j = 0; j < 4; ++j) {
        int rW = (wid + 4 * j) * 16 + rseg;
        gW1[j] = (const char*)W1t + (size_t)rW * (K1 * 2) + sw * 16;
        gW2[j] = (const char*)W2t + (size_t)rW * 512 + sw * 16;
    }

    // issue W1 tile 0 (lands during gather)
    #pragma unroll
    for (int j = 0; j < 4; ++j)
        gl16(gW1[j], WB + (wid + 4 * j) * 1024);

    // ---- gather phase: wave wid owns rows wid*16..wid*16+15 ----
    constexpr int PER = K1 / 64;       // dims per lane (2 or 4)
    constexpr int ROWB = K1 * 2;       // A row bytes (256 or 512)
    for (int i = 0; i < 16; ++i) {
        int r = wid * 16 + i;
        int node = m0 + r;
        float a[PER];
        #pragma unroll
        for (int p = 0; p < PER; ++p) a[p] = 0.f;
        if (node < N_NODES) {
            const __hip_bfloat16* xr = X + (size_t)node * K1 + lane * PER;
            if constexpr (PER == 4) {
                ushort4 v = *reinterpret_cast<const ushort4*>(xr);
                a[0] = bf2f(v.x); a[1] = bf2f(v.y); a[2] = bf2f(v.z); a[3] = bf2f(v.w);
            } else {
                ushort2 v = *reinterpret_cast<const ushort2*>(xr);
                a[0] = bf2f(v.x); a[1] = bf2f(v.y);
            }
            int s = row_ptr[node], e = row_ptr[node + 1];
            int k = s;
            if constexpr (PER == 4) {
                for (; k + 8 <= e; k += 8) {
                    ushort4 u[8];
                    #pragma unroll
                    for (int j = 0; j < 8; ++j)
                        u[j] = *reinterpret_cast<const ushort4*>(X + (size_t)col[k + j] * K1 + lane * 4);
                    #pragma unroll
                    for (int j = 0; j < 8; ++j) {
                        a[0] += bf2f(u[j].x); a[1] += bf2f(u[j].y);
                        a[2] += bf2f(u[j].z); a[3] += bf2f(u[j].w);
                    }
                }
                for (; k < e; ++k) {
                    ushort4 u = *reinterpret_cast<const ushort4*>(X + (size_t)col[k] * K1 + lane * 4);
                    a[0] += bf2f(u.x); a[1] += bf2f(u.y); a[2] += bf2f(u.z); a[3] += bf2f(u.w);
                }
            } else {
                for (; k + 8 <= e; k += 8) {
                    ushort2 u[8];
                    #pragma unroll
                    for (int j = 0; j < 8; ++j)
                        u[j] = *reinterpret_cast<const ushort2*>(X + (size_t)col[k + j] * K1 + lane * 2);
                    #pragma unroll
                    for (int j = 0; j < 8; ++j) { a[0] += bf2f(u[j].x); a[1] += bf2f(u[j].y); }
                }
                for (; k < e; ++k) {
                    ushort2 u = *reinterpret_cast<const ushort2*>(X + (size_t)col[k] * K1 + lane * 2);
                    a[0] += bf2f(u.x); a[1] += bf2f(u.y);
                }
            }
        }
        // write A row r to LDS with 16B-chunk XOR swizzle (chunk ^= r&7)
        if constexpr (PER == 4) {
            ushort4 o;
            o.x = f2bf(a[0]); o.y = f2bf(a[1]); o.z = f2bf(a[2]); o.w = f2bf(a[3]);
            int addr = r * ROWB + (((lane >> 1) ^ (r & 7)) << 4) + (lane & 1) * 8;
            *reinterpret_cast<ushort4*>(AT + addr) = o;
        } else {
            ushort2 o;
            o.x = f2bf(a[0]); o.y = f2bf(a[1]);
            int addr = r * ROWB + (((lane >> 2) ^ (r & 7)) << 4) + (lane & 3) * 4;
            *reinterpret_cast<ushort2*>(AT + addr) = o;
        }
    }
    __syncthreads();   // gather writes + W1 tile0 (full drain)

    // ---- stage 1: acc1 = A @ W1t^T ----
    f32x4 acc1[4][4] = {};
    constexpr int NT1 = K1 / 32;
    #pragma unroll 1
    for (int t = 0; t < NT1; ++t) {
        int cur = t & 1;
        if (t + 1 < NT1) {
            char* l = WB + (cur ^ 1) * 16384;
            #pragma unroll
            for (int j = 0; j < 4; ++j)
                gl16(gW1[j] + (t + 1) * 64, l + (wid + 4 * j) * 1024);
            vmwait<4>();
        } else {
            vmwait<0>();
        }
        bar();
        const char* Bs = WB + cur * 16384;
        bf16x8 af[4], bv[4];
        #pragma unroll
        for (int m = 0; m < 4; ++m) {
            int row = m * 16 + r16;
            int c = (4 * t + g) ^ (row & 7);
            af[m] = *reinterpret_cast<const bf16x8*>(AT + row * ROWB + c * 16);
        }
        #pragma unroll
        for (int n = 0; n < 4; ++n)
            bv[n] = *reinterpret_cast<const bf16x8*>(Bs + (wid * 64 + n * 16 + r16) * 64 + gg * 16);
        __builtin_amdgcn_s_setprio(1);
        #pragma unroll
        for (int m = 0; m < 4; ++m)
            #pragma unroll
            for (int n = 0; n < 4; ++n)
                acc1[m][n] = __builtin_amdgcn_mfma_f32_16x16x32_bf16(af[m], bv[n], acc1[m][n], 0, 0, 0);
        __builtin_amdgcn_s_setprio(0);
        bar();
    }

    // issue W2 tile 0 early (hides under epilogue 1)
    #pragma unroll
    for (int j = 0; j < 4; ++j)
        gl16(gW2[j], WB + (wid + 4 * j) * 1024);

    // epilogue 1: bias+relu -> bf16 mid into AT (512B rows, chunk ^= row&7)
    // C/D layout: col = lane&15, row = g*4 + reg
    #pragma unroll
    for (int m = 0; m < 4; ++m) {
        #pragma unroll
        for (int n = 0; n < 4; ++n) {
            int colX = wid * 64 + n * 16 + r16;
            float bb = b1[colX];
            int cb = colX >> 3;
            int within = (colX & 7) * 2;
            #pragma unroll
            for (int r = 0; r < 4; ++r) {
                int row = m * 16 + g * 4 + r;
                float v = fmaxf(acc1[m][n][r] + bb, 0.f);
                *reinterpret_cast<unsigned short*>(
                    AT + row * 512 + ((cb ^ (row & 7)) << 4) + within) = f2bf(v);
            }
        }
    }
    __syncthreads();   // mid visible + W2 tile0 drained

    // ---- stage 2: acc2 = mid @ W2t^T ----
    f32x4 acc2[4][4] = {};
    #pragma unroll 1
    for (int t = 0; t < 8; ++t) {
        int cur = t & 1;
        if (t + 1 < 8) {
            char* l = WB + (cur ^ 1) * 16384;
            #pragma unroll
            for (int j = 0; j < 4; ++j)
                gl16(gW2[j] + (t + 1) * 64, l + (wid + 4 * j) * 1024);
            vmwait<4>();
        } else {
            vmwait<0>();
        }
        bar();
        const char* Bs = WB + cur * 16384;
        bf16x8 af[4], bv[4];
        #pragma unroll
        for (int m = 0; m < 4; ++m) {
            int row = m * 16 + r16;
            int c = (4 * t + g) ^ (row & 7);
            af[m] = *reinterpret_cast<const bf16x8*>(AT + row * 512 + c * 16);
        }
        #pragma unroll
        for (int n = 0; n < 4; ++n)
            bv[n] = *reinterpret_cast<const bf16x8*>(Bs + (wid * 64 + n * 16 + r16) * 64 + gg * 16);
        __builtin_amdgcn_s_setprio(1);
        #pragma unroll
        for (int m = 0; m < 4; ++m)
            #pragma unroll
            for (int n = 0; n < 4; ++n)
                acc2[m][n] = __builtin_amdgcn_mfma_f32_16x16x32_bf16(af[m], bv[n], acc2[m][n], 0, 0, 0);
        __builtin_amdgcn_s_setprio(0);
        bar();
    }

    // epilogue 2: bias+relu -> C
    #pragma unroll
    for (int m = 0; m < 4; ++m) {
        #pragma unroll
        for (int n = 0; n < 4; ++n) {
            int colX = wid * 64 + n * 16 + r16;
            float bb = b2[colX];
            #pragma unroll
            for (int r = 0; r < 4; ++r) {
                int row = m0 + m * 16 + g * 4 + r;
                float v = fmaxf(acc2[m][n][r] + bb, 0.f);
                C[(size_t)row * HID + colX] = __float2bfloat16(v);
            }
        }
    }
}

// ---------------------------------------------------------------------------
// pooling: per-block register acc over 128 sorted nodes, atomic flush at
// graph boundaries. pooled zeroed by transpose_all z=6.
__global__ __launch_bounds__(256) void pool_partial(
    const __hip_bfloat16* __restrict__ h, const int* __restrict__ batch,
    float* __restrict__ pooled)
{
    __shared__ int sb[128];
    int n0 = blockIdx.x * 128;
    int cnt = N_NODES - n0; if (cnt > 128) cnt = 128;
    int d = threadIdx.x;
    if (d < cnt) sb[d] = batch[n0 + d];
    __syncthreads();
    float acc = 0.f;
    int cur = sb[0];
    for (int i = 0; i < cnt; ++i) {
        int g = sb[i];
        if (g != cur) { atomicAdd(&pooled[cur * HID + d], acc); acc = 0.f; cur = g; }
        acc += bf2f(*reinterpret_cast<const unsigned short*>(h + (size_t)(n0 + i) * HID + d));
    }
    atomicAdd(&pooled[cur * HID + d], acc);
}

// head: logits = pooled @ wl + bl ; log_softmax
__global__ __launch_bounds__(256) void head_kernel(
    const float* __restrict__ pooled, const float* __restrict__ wl,
    const float* __restrict__ bl, float* __restrict__ out)
{
    int gph = blockIdx.x;
    int d = threadIdx.x;
    __shared__ float p[HID];
    __shared__ float logits[OUT_DIM];
    __shared__ float lse_s;
    p[d] = pooled[gph * HID + d];
    __syncthreads();
    if (d < OUT_DIM) {
        float v = bl[d];
        for (int k = 0; k < HID; ++k) v += p[k] * wl[k * OUT_DIM + d];
        logits[d] = v;
    }
    __syncthreads();
    if (d == 0) {
        float mx = logits[0];
        for (int j = 1; j < OUT_DIM; ++j) mx = fmaxf(mx, logits[j]);
        float s = 0.f;
        for (int j = 0; j < OUT_DIM; ++j) s += expf(logits[j] - mx);
        lse_s = mx + logf(s);
    }
    __syncthreads();
    if (d < OUT_DIM) out[gph * OUT_DIM + d] = logits[d] - lse_s;
}

// ---------------------------------------------------------------------------
extern "C" void kernel_launch(void* const* d_in, const int* in_sizes, int n_in,
                              void* d_out, int out_size, void* d_ws, size_t ws_size,
                              hipStream_t stream) {
    const float* x    = (const float*)d_in[0];
    const int*   ei   = (const int*)d_in[1];
    const int*   batch= (const int*)d_in[2];
    const float* w1a  = (const float*)d_in[3];
    const float* b1a  = (const float*)d_in[4];
    const float* w1b  = (const float*)d_in[5];
    const float* b1b  = (const float*)d_in[6];
    const float* w2a  = (const float*)d_in[7];
    const float* b2a  = (const float*)d_in[8];
    const float* w2b  = (const float*)d_in[9];
    const float* b2b  = (const float*)d_in[10];
    const float* w3a  = (const float*)d_in[11];
    const float* b3a  = (const float*)d_in[12];
    const float* w3b  = (const float*)d_in[13];
    const float* b3b  = (const float*)d_in[14];
    const float* wl   = (const float*)d_in[15];
    const float* bl   = (const float*)d_in[16];

    const int* src = ei;
    const int* dst = ei + N_EDGES;

    __hip_bfloat16* bufA = (__hip_bfloat16*)d_ws;                  // M_PAD*256
    __hip_bfloat16* bufB = bufA + (size_t)M_PAD * HID;             // M_PAD*256
    __hip_bfloat16* x_bf = bufB + (size_t)M_PAD * HID;             // N_NODES*128
    __hip_bfloat16* wt1a = x_bf + (size_t)N_NODES * IN_DIM;        // 256*128
    __hip_bfloat16* wt1b = wt1a + HID * IN_DIM;                    // 256*256
    __hip_bfloat16* wt2a = wt1b + HID * HID;
    __hip_bfloat16* wt2b = wt2a + HID * HID;
    __hip_bfloat16* wt3a = wt2b + HID * HID;
    __hip_bfloat16* wt3b = wt3a + HID * HID;
    float* pooled = (float*)(wt3b + HID * HID);                    // 64*256
    int* deg     = (int*)(pooled + N_GRAPHS * HID);                // contiguous w/ pooled
    int* row_ptr = deg + N_NODES;
    int* pos     = row_ptr + (N_NODES + 1);
    int* col     = pos + N_NODES;                                  // N_EDGES

    float* out = (float*)d_out;

    // ---- prep: weights transpose, zero pooled/deg, x->bf16 (one kernel) ----
    int zn = N_GRAPHS * HID + N_NODES;
    int n4 = N_NODES * IN_DIM / 4;
    transpose_all<<<dim3(8, 8, 8), 256, 0, stream>>>(
        w1a, w1b, w2a, w2b, w3a, w3b, wt1a, wt1b, wt2a, wt2b, wt3a, wt3b,
        (int*)pooled, zn, x, x_bf, n4);

    degree_hist<<<(N_EDGES + 255) / 256, 256, 0, stream>>>(dst, deg, N_EDGES);
    scan_deg<<<1, 1024, 0, stream>>>(deg, row_ptr, pos, N_NODES);
    csr_fill<<<(N_EDGES + 255) / 256, 256, 0, stream>>>(src, dst, pos, col, N_EDGES);

    int mlp_blocks = M_PAD / 64;

    // ---- fused layers (gather + 2-layer MLP each) ----
    gin_mlp<IN_DIM><<<mlp_blocks, 256, 0, stream>>>(x_bf, row_ptr, col, wt1a, b1a, wt1b, b1b, bufB);
    gin_mlp<HID><<<mlp_blocks, 256, 0, stream>>>(bufB, row_ptr, col, wt2a, b2a, wt2b, b2b, bufA);
    gin_mlp<HID><<<mlp_blocks, 256, 0, stream>>>(bufA, row_ptr, col, wt3a, b3a, wt3b, b3b, bufB);

    // ---- pool + head ----
    pool_partial<<<(N_NODES + 127) / 128, 256, 0, stream>>>(bufB, batch, pooled);
    head_kernel<<<N_GRAPHS, 256, 0, stream>>>(pooled, wl, bl, out);
}

// Round 8
// 254.655 us; speedup vs baseline: 1.3723x; 1.3723x over previous
//
#include <hip/hip_runtime.h>
#include <hip/hip_bf16.h>

#define N_NODES 20000
#define M_PAD 20096            // 314 * 64
#define IN_DIM 128
#define HID 256
#define OUT_DIM 10
#define N_EDGES 320000
#define N_GRAPHS 64

typedef __attribute__((ext_vector_type(8))) short bf16x8;
typedef __attribute__((ext_vector_type(8))) unsigned short u16x8;
typedef __attribute__((ext_vector_type(4))) float f32x4;

__device__ inline float bf2f(unsigned short u) {
    return __uint_as_float((unsigned int)u << 16);
}
__device__ inline unsigned short f2bf(float f) {
    __hip_bfloat16 h = __float2bfloat16(f);
    return *reinterpret_cast<unsigned short*>(&h);
}

__device__ __forceinline__ void gl16(const void* g, void* l) {
    __builtin_amdgcn_global_load_lds(
        (const __attribute__((address_space(1))) unsigned int*)g,
        (__attribute__((address_space(3))) unsigned int*)l, 16, 0, 0);
}

// ---------------------------------------------------------------------------
// CSR build
__global__ void degree_hist(const int* __restrict__ dst, int* __restrict__ deg, int n) {
    int i = blockIdx.x * blockDim.x + threadIdx.x;
    int stride = gridDim.x * blockDim.x;
    for (; i < n; i += stride) atomicAdd(&deg[dst[i]], 1);
}

__global__ __launch_bounds__(1024) void scan_deg(const int* __restrict__ deg,
                                                 int* __restrict__ row_ptr,
                                                 int* __restrict__ pos, int n) {
    __shared__ int sums[1024];
    int tid = threadIdx.x;
    int chunk = (n + 1023) / 1024;
    int base = tid * chunk;
    int s = 0;
    for (int i = 0; i < chunk; ++i) {
        int idx = base + i;
        if (idx < n) s += deg[idx];
    }
    sums[tid] = s;
    __syncthreads();
    for (int off = 1; off < 1024; off <<= 1) {
        int v = (tid >= off) ? sums[tid - off] : 0;
        __syncthreads();
        if (tid >= off) sums[tid] += v;
        __syncthreads();
    }
    int run = (tid == 0) ? 0 : sums[tid - 1];
    for (int i = 0; i < chunk; ++i) {
        int idx = base + i;
        if (idx < n) {
            row_ptr[idx] = run;
            pos[idx] = run;
            run += deg[idx];
            if (idx == n - 1) row_ptr[n] = run;
        }
    }
}

__global__ void csr_fill(const int* __restrict__ src, const int* __restrict__ dst,
                         int* __restrict__ pos, int* __restrict__ col, int n) {
    int i = blockIdx.x * blockDim.x + threadIdx.x;
    int stride = gridDim.x * blockDim.x;
    for (; i < n; i += stride) {
        int slot = atomicAdd(&pos[dst[i]], 1);
        col[slot] = src[i];
    }
}

// ---------------------------------------------------------------------------
// batched prep: z<6 weight transpose+convert; z==6 zero pooled/deg; z==7 x->bf16
__global__ __launch_bounds__(256) void transpose_all(
    const float* __restrict__ w1a, const float* __restrict__ w1b,
    const float* __restrict__ w2a, const float* __restrict__ w2b,
    const float* __restrict__ w3a, const float* __restrict__ w3b,
    __hip_bfloat16* __restrict__ o1a, __hip_bfloat16* __restrict__ o1b,
    __hip_bfloat16* __restrict__ o2a, __hip_bfloat16* __restrict__ o2b,
    __hip_bfloat16* __restrict__ o3a, __hip_bfloat16* __restrict__ o3b,
    int* __restrict__ zp, int zn,
    const float* __restrict__ x, __hip_bfloat16* __restrict__ x_bf, int n4)
{
    __shared__ float tile[32][33];
    int z = blockIdx.z;
    if (z == 6) {
        int i = (blockIdx.y * 8 + blockIdx.x) * 256 + threadIdx.x;
        for (; i < zn; i += 64 * 256) zp[i] = 0;
        return;
    }
    if (z == 7) {
        int i = (blockIdx.y * 8 + blockIdx.x) * 256 + threadIdx.x;
        for (; i < n4; i += 64 * 256) {
            float4 v = reinterpret_cast<const float4*>(x)[i];
            ushort4 u;
            u.x = f2bf(v.x); u.y = f2bf(v.y); u.z = f2bf(v.z); u.w = f2bf(v.w);
            reinterpret_cast<ushort4*>(x_bf)[i] = u;
        }
        return;
    }
    const float* in = (z == 0) ? w1a : (z == 1) ? w1b : (z == 2) ? w2a
                    : (z == 3) ? w2b : (z == 4) ? w3a : w3b;
    __hip_bfloat16* out = (z == 0) ? o1a : (z == 1) ? o1b : (z == 2) ? o2a
                        : (z == 3) ? o2b : (z == 4) ? o3a : o3b;
    int rows = (z == 0) ? IN_DIM : HID;
    int r0 = blockIdx.y * 32;
    if (r0 >= rows) return;
    int c0 = blockIdx.x * 32;
    int tx = threadIdx.x & 31, ty = threadIdx.x >> 5;
    for (int i = ty; i < 32; i += 8)
        tile[i][tx] = in[(size_t)(r0 + i) * HID + c0 + tx];
    __syncthreads();
    for (int i = ty; i < 32; i += 8)
        out[(size_t)(c0 + i) * rows + r0 + tx] = __float2bfloat16(tile[tx][i]);
}

// ---------------------------------------------------------------------------
// gather-aggregate D=256: one wave per node; 16B/lane, half-wave per row
// -> 2 edges per load slot, 16 edges in flight per unrolled iter.
__global__ __launch_bounds__(256) void gin_agg256(
    const __hip_bfloat16* __restrict__ X, const int* __restrict__ row_ptr,
    const int* __restrict__ col, __hip_bfloat16* __restrict__ out)
{
    int node = blockIdx.x * 4 + (threadIdx.x >> 6);
    if (node >= N_NODES) return;
    int lane = threadIdx.x & 63;
    int half = lane >> 5;            // which edge of the pair
    int doff = (lane & 31) * 8;      // 8 dims (16B) per lane

    const unsigned short* Xu = (const unsigned short*)X;

    float acc[8];
    #pragma unroll
    for (int p = 0; p < 8; ++p) acc[p] = 0.f;

    if (half == 0) {
        u16x8 v = *reinterpret_cast<const u16x8*>(Xu + (size_t)node * 256 + doff);
        #pragma unroll
        for (int p = 0; p < 8; ++p) acc[p] = bf2f(v[p]);
    }

    int s = row_ptr[node], e = row_ptr[node + 1];
    int k = s;
    for (; k + 16 <= e; k += 16) {
        u16x8 u[8];
        #pragma unroll
        for (int j = 0; j < 8; ++j)
            u[j] = *reinterpret_cast<const u16x8*>(Xu + (size_t)col[k + 2 * j + half] * 256 + doff);
        #pragma unroll
        for (int j = 0; j < 8; ++j)
            #pragma unroll
            for (int p = 0; p < 8; ++p) acc[p] += bf2f(u[j][p]);
    }
    for (; k < e; k += 2) {
        int ke = k + half;
        if (ke < e) {
            u16x8 u = *reinterpret_cast<const u16x8*>(Xu + (size_t)col[ke] * 256 + doff);
            #pragma unroll
            for (int p = 0; p < 8; ++p) acc[p] += bf2f(u[p]);
        }
    }
    #pragma unroll
    for (int p = 0; p < 8; ++p) acc[p] += __shfl_xor(acc[p], 32, 64);
    if (half == 0) {
        u16x8 o;
        #pragma unroll
        for (int p = 0; p < 8; ++p) o[p] = f2bf(acc[p]);
        *reinterpret_cast<u16x8*>((unsigned short*)out + (size_t)node * 256 + doff) = o;
    }
}

// gather-aggregate D=128: quarter-wave per row -> 4 edges per load slot.
__global__ __launch_bounds__(256) void gin_agg128(
    const __hip_bfloat16* __restrict__ X, const int* __restrict__ row_ptr,
    const int* __restrict__ col, __hip_bfloat16* __restrict__ out)
{
    int node = blockIdx.x * 4 + (threadIdx.x >> 6);
    if (node >= N_NODES) return;
    int lane = threadIdx.x & 63;
    int q = lane >> 4;               // which edge of the quad
    int doff = (lane & 15) * 8;

    const unsigned short* Xu = (const unsigned short*)X;

    float acc[8];
    #pragma unroll
    for (int p = 0; p < 8; ++p) acc[p] = 0.f;

    if (q == 0) {
        u16x8 v = *reinterpret_cast<const u16x8*>(Xu + (size_t)node * 128 + doff);
        #pragma unroll
        for (int p = 0; p < 8; ++p) acc[p] = bf2f(v[p]);
    }

    int s = row_ptr[node], e = row_ptr[node + 1];
    int k = s;
    for (; k + 16 <= e; k += 16) {
        u16x8 u[4];
        #pragma unroll
        for (int j = 0; j < 4; ++j)
            u[j] = *reinterpret_cast<const u16x8*>(Xu + (size_t)col[k + 4 * j + q] * 128 + doff);
        #pragma unroll
        for (int j = 0; j < 4; ++j)
            #pragma unroll
            for (int p = 0; p < 8; ++p) acc[p] += bf2f(u[j][p]);
    }
    for (; k < e; k += 4) {
        int ke = k + q;
        if (ke < e) {
            u16x8 u = *reinterpret_cast<const u16x8*>(Xu + (size_t)col[ke] * 128 + doff);
            #pragma unroll
            for (int p = 0; p < 8; ++p) acc[p] += bf2f(u[p]);
        }
    }
    #pragma unroll
    for (int p = 0; p < 8; ++p) {
        acc[p] += __shfl_xor(acc[p], 16, 64);
        acc[p] += __shfl_xor(acc[p], 32, 64);
    }
    if (q == 0) {
        u16x8 o;
        #pragma unroll
        for (int p = 0; p < 8; ++p) o[p] = f2bf(acc[p]);
        *reinterpret_cast<u16x8*>((unsigned short*)out + (size_t)node * 128 + doff) = o;
    }
}

// ---------------------------------------------------------------------------
// fused per-layer MLP: C = relu(relu(A @ W1t^T + b1) @ W2t^T + b2)
// BM=64, BN=256; 4 waves; plain-__syncthreads double-buffered gload_lds staging.
template<int K1>
__global__ __launch_bounds__(256) void gin_mlp(
    const __hip_bfloat16* __restrict__ A, const __hip_bfloat16* __restrict__ W1t,
    const float* __restrict__ b1, const __hip_bfloat16* __restrict__ W2t,
    const float* __restrict__ b2, __hip_bfloat16* __restrict__ C)
{
    __shared__ int4 smem4[4608];       // 73728 B
    char* smem = (char*)smem4;
    char* mid = smem + 40960;          // 64 x 512B

    int tid = threadIdx.x;
    int lane = tid & 63;
    int wid = tid >> 6;                // wave -> col slice
    int m0 = blockIdx.x * 64;

    int r16 = lane & 15;
    int g = lane >> 4;
    int gg = g ^ ((r16 >> 1) & 3);     // read-side chunk swizzle (64B-row tiles)

    // staging: lane -> dest row (lane>>2), dest chunk (lane&3);
    // source chunk pre-swizzled so LDS[row][p] holds src chunk p^((row>>1)&3)
    int rseg = lane >> 2;
    int sw = (lane & 3) ^ ((lane >> 3) & 3);
    int rA = wid * 16 + rseg;

    const char* gA = (const char*)A + (size_t)(m0 + rA) * (K1 * 2) + sw * 16;
    const char* gW1[4];
    #pragma unroll
    for (int j = 0; j < 4; ++j) {
        int rW = (wid + 4 * j) * 16 + rseg;
        gW1[j] = (const char*)W1t + (size_t)rW * (K1 * 2) + sw * 16;
    }

    auto stage1 = [&](int buf, int t) {
        char* l = smem + buf * 20480;
        gl16(gA + t * 64, l + wid * 1024);
        #pragma unroll
        for (int j = 0; j < 4; ++j)
            gl16(gW1[j] + t * 64, l + 4096 + (wid + 4 * j) * 1024);
    };

    // ---- stage 1: mid = relu(A @ W1t^T + b1) ----
    f32x4 acc[4][4] = {};
    constexpr int NT1 = K1 / 32;

    stage1(0, 0);
    __syncthreads();
    #pragma unroll
    for (int t = 0; t < NT1; ++t) {
        int cur = t & 1;
        if (t + 1 < NT1) stage1(cur ^ 1, t + 1);
        const char* As = smem + cur * 20480;
        const char* Bs = As + 4096;
        bf16x8 af[4], bfv[4];
        #pragma unroll
        for (int m = 0; m < 4; ++m)
            af[m] = *reinterpret_cast<const bf16x8*>(As + (m * 16 + r16) * 64 + gg * 16);
        #pragma unroll
        for (int n = 0; n < 4; ++n)
            bfv[n] = *reinterpret_cast<const bf16x8*>(Bs + (wid * 64 + n * 16 + r16) * 64 + gg * 16);
        #pragma unroll
        for (int m = 0; m < 4; ++m)
            #pragma unroll
            for (int n = 0; n < 4; ++n)
                acc[m][n] = __builtin_amdgcn_mfma_f32_16x16x32_bf16(af[m], bfv[n], acc[m][n], 0, 0, 0);
        __syncthreads();
    }

    // issue W2 tile 0 early (hides under epilogue 1)
    const char* gW2[4];
    #pragma unroll
    for (int j = 0; j < 4; ++j) {
        int rW = (wid + 4 * j) * 16 + rseg;
        gW2[j] = (const char*)W2t + (size_t)rW * 512 + sw * 16;
    }
    auto stageW2 = [&](int buf, int t) {
        char* l = smem + buf * 16384;
        #pragma unroll
        for (int j = 0; j < 4; ++j)
            gl16(gW2[j] + t * 64, l + (wid + 4 * j) * 1024);
    };
    stageW2(0, 0);

    // epilogue 1: bias+relu -> bf16 -> mid (swizzled). C/D: col=lane&15, row=g*4+reg
    #pragma unroll
    for (int m = 0; m < 4; ++m) {
        #pragma unroll
        for (int n = 0; n < 4; ++n) {
            int colX = wid * 64 + n * 16 + r16;
            float bb = b1[colX];
            int cb = colX >> 3;
            int within = (colX & 7) * 2;
            #pragma unroll
            for (int r = 0; r < 4; ++r) {
                int row = m * 16 + g * 4 + r;
                float v = fmaxf(acc[m][n][r] + bb, 0.f);
                *reinterpret_cast<unsigned short*>(
                    mid + row * 512 + ((cb ^ (row & 7)) << 4) + within) = f2bf(v);
            }
        }
    }

    __syncthreads();   // drains vmcnt+lgkm: W2 tile0 ready, mid visible

    // ---- stage 2: C = relu(mid @ W2t^T + b2) ----
    f32x4 acc2[4][4] = {};
    #pragma unroll
    for (int t = 0; t < 8; ++t) {
        int cur = t & 1;
        if (t + 1 < 8) stageW2(cur ^ 1, t + 1);
        const char* Bs = smem + cur * 16384;
        bf16x8 af[4], bfv[4];
        #pragma unroll
        for (int m = 0; m < 4; ++m) {
            int row = m * 16 + r16;
            int c = (t * 4 + g) ^ (row & 7);
            af[m] = *reinterpret_cast<const bf16x8*>(mid + row * 512 + c * 16);
        }
        #pragma unroll
        for (int n = 0; n < 4; ++n)
            bfv[n] = *reinterpret_cast<const bf16x8*>(Bs + (wid * 64 + n * 16 + r16) * 64 + gg * 16);
        #pragma unroll
        for (int m = 0; m < 4; ++m)
            #pragma unroll
            for (int n = 0; n < 4; ++n)
                acc2[m][n] = __builtin_amdgcn_mfma_f32_16x16x32_bf16(af[m], bfv[n], acc2[m][n], 0, 0, 0);
        __syncthreads();
    }

    // epilogue 2: bias+relu -> C
    #pragma unroll
    for (int m = 0; m < 4; ++m) {
        #pragma unroll
        for (int n = 0; n < 4; ++n) {
            int colX = wid * 64 + n * 16 + r16;
            float bb = b2[colX];
            #pragma unroll
            for (int r = 0; r < 4; ++r) {
                int row = m0 + m * 16 + g * 4 + r;
                float v = fmaxf(acc2[m][n][r] + bb, 0.f);
                C[(size_t)row * HID + colX] = __float2bfloat16(v);
            }
        }
    }
}

// ---------------------------------------------------------------------------
// pooling: per-block register acc over 128 sorted nodes, atomic flush at
// graph boundaries. pooled zeroed by transpose_all z=6.
__global__ __launch_bounds__(256) void pool_partial(
    const __hip_bfloat16* __restrict__ h, const int* __restrict__ batch,
    float* __restrict__ pooled)
{
    __shared__ int sb[128];
    int n0 = blockIdx.x * 128;
    int cnt = N_NODES - n0; if (cnt > 128) cnt = 128;
    int d = threadIdx.x;
    if (d < cnt) sb[d] = batch[n0 + d];
    __syncthreads();
    float acc = 0.f;
    int cur = sb[0];
    for (int i = 0; i < cnt; ++i) {
        int g = sb[i];
        if (g != cur) { atomicAdd(&pooled[cur * HID + d], acc); acc = 0.f; cur = g; }
        acc += bf2f(*reinterpret_cast<const unsigned short*>(h + (size_t)(n0 + i) * HID + d));
    }
    atomicAdd(&pooled[cur * HID + d], acc);
}

// head: logits = pooled @ wl + bl ; log_softmax
__global__ __launch_bounds__(256) void head_kernel(
    const float* __restrict__ pooled, const float* __restrict__ wl,
    const float* __restrict__ bl, float* __restrict__ out)
{
    int gph = blockIdx.x;
    int d = threadIdx.x;
    __shared__ float p[HID];
    __shared__ float logits[OUT_DIM];
    __shared__ float lse_s;
    p[d] = pooled[gph * HID + d];
    __syncthreads();
    if (d < OUT_DIM) {
        float v = bl[d];
        for (int k = 0; k < HID; ++k) v += p[k] * wl[k * OUT_DIM + d];
        logits[d] = v;
    }
    __syncthreads();
    if (d == 0) {
        float mx = logits[0];
        for (int j = 1; j < OUT_DIM; ++j) mx = fmaxf(mx, logits[j]);
        float s = 0.f;
        for (int j = 0; j < OUT_DIM; ++j) s += expf(logits[j] - mx);
        lse_s = mx + logf(s);
    }
    __syncthreads();
    if (d < OUT_DIM) out[gph * OUT_DIM + d] = logits[d] - lse_s;
}

// ---------------------------------------------------------------------------
extern "C" void kernel_launch(void* const* d_in, const int* in_sizes, int n_in,
                              void* d_out, int out_size, void* d_ws, size_t ws_size,
                              hipStream_t stream) {
    const float* x    = (const float*)d_in[0];
    const int*   ei   = (const int*)d_in[1];
    const int*   batch= (const int*)d_in[2];
    const float* w1a  = (const float*)d_in[3];
    const float* b1a  = (const float*)d_in[4];
    const float* w1b  = (const float*)d_in[5];
    const float* b1b  = (const float*)d_in[6];
    const float* w2a  = (const float*)d_in[7];
    const float* b2a  = (const float*)d_in[8];
    const float* w2b  = (const float*)d_in[9];
    const float* b2b  = (const float*)d_in[10];
    const float* w3a  = (const float*)d_in[11];
    const float* b3a  = (const float*)d_in[12];
    const float* w3b  = (const float*)d_in[13];
    const float* b3b  = (const float*)d_in[14];
    const float* wl   = (const float*)d_in[15];
    const float* bl   = (const float*)d_in[16];

    const int* src = ei;
    const int* dst = ei + N_EDGES;

    __hip_bfloat16* bufA = (__hip_bfloat16*)d_ws;                  // M_PAD*256
    __hip_bfloat16* bufB = bufA + (size_t)M_PAD * HID;             // M_PAD*256
    __hip_bfloat16* x_bf = bufB + (size_t)M_PAD * HID;             // N_NODES*128
    __hip_bfloat16* wt1a = x_bf + (size_t)N_NODES * IN_DIM;        // 256*128
    __hip_bfloat16* wt1b = wt1a + HID * IN_DIM;                    // 256*256
    __hip_bfloat16* wt2a = wt1b + HID * HID;
    __hip_bfloat16* wt2b = wt2a + HID * HID;
    __hip_bfloat16* wt3a = wt2b + HID * HID;
    __hip_bfloat16* wt3b = wt3a + HID * HID;
    float* pooled = (float*)(wt3b + HID * HID);                    // 64*256
    int* deg     = (int*)(pooled + N_GRAPHS * HID);                // contiguous w/ pooled
    int* row_ptr = deg + N_NODES;
    int* pos     = row_ptr + (N_NODES + 1);
    int* col     = pos + N_NODES;                                  // N_EDGES

    float* out = (float*)d_out;

    // ---- prep: weights transpose, zero pooled/deg, x->bf16 (one kernel) ----
    int zn = N_GRAPHS * HID + N_NODES;
    int n4 = N_NODES * IN_DIM / 4;
    transpose_all<<<dim3(8, 8, 8), 256, 0, stream>>>(
        w1a, w1b, w2a, w2b, w3a, w3b, wt1a, wt1b, wt2a, wt2b, wt3a, wt3b,
        (int*)pooled, zn, x, x_bf, n4);

    degree_hist<<<(N_EDGES + 255) / 256, 256, 0, stream>>>(dst, deg, N_EDGES);
    scan_deg<<<1, 1024, 0, stream>>>(deg, row_ptr, pos, N_NODES);
    csr_fill<<<(N_EDGES + 255) / 256, 256, 0, stream>>>(src, dst, pos, col, N_EDGES);

    int agg_blocks = (N_NODES + 3) / 4;
    int mlp_blocks = M_PAD / 64;

    // ---- layer 1 ----
    gin_agg128<<<agg_blocks, 256, 0, stream>>>(x_bf, row_ptr, col, bufA);
    gin_mlp<IN_DIM><<<mlp_blocks, 256, 0, stream>>>(bufA, wt1a, b1a, wt1b, b1b, bufB);

    // ---- layer 2 ----
    gin_agg256<<<agg_blocks, 256, 0, stream>>>(bufB, row_ptr, col, bufA);
    gin_mlp<HID><<<mlp_blocks, 256, 0, stream>>>(bufA, wt2a, b2a, wt2b, b2b, bufB);

    // ---- layer 3 ----
    gin_agg256<<<agg_blocks, 256, 0, stream>>>(bufB, row_ptr, col, bufA);
    gin_mlp<HID><<<mlp_blocks, 256, 0, stream>>>(bufA, wt3a, b3a, wt3b, b3b, bufB);

    // ---- pool + head ----
    pool_partial<<<(N_NODES + 127) / 128, 256, 0, stream>>>(bufB, batch, pooled);
    head_kernel<<<N_GRAPHS, 256, 0, stream>>>(pooled, wl, bl, out);
}

// Round 9
// 226.144 us; speedup vs baseline: 1.5453x; 1.1261x over previous
//
#include <hip/hip_runtime.h>
#include <hip/hip_bf16.h>

#define N_NODES 20000
#define M_PAD 20096            // 314 * 64
#define IN_DIM 128
#define HID 256
#define OUT_DIM 10
#define N_EDGES 320000
#define N_GRAPHS 64

typedef __attribute__((ext_vector_type(8))) short bf16x8;
typedef __attribute__((ext_vector_type(4))) float f32x4;
typedef __attribute__((ext_vector_type(2))) float f32x2;

__device__ inline float bf2f(unsigned short u) {
    return __uint_as_float((unsigned int)u << 16);
}
__device__ inline unsigned short f2bf(float f) {
    __hip_bfloat16 h = __float2bfloat16(f);
    return *reinterpret_cast<unsigned short*>(&h);
}

__device__ __forceinline__ void gl16(const void* g, void* l) {
    __builtin_amdgcn_global_load_lds(
        (const __attribute__((address_space(1))) unsigned int*)g,
        (__attribute__((address_space(3))) unsigned int*)l, 16, 0, 0);
}

// ---------------------------------------------------------------------------
// CSR build
__global__ void degree_hist(const int* __restrict__ dst, int* __restrict__ deg, int n) {
    int i = blockIdx.x * blockDim.x + threadIdx.x;
    int stride = gridDim.x * blockDim.x;
    for (; i < n; i += stride) atomicAdd(&deg[dst[i]], 1);
}

__global__ __launch_bounds__(1024) void scan_deg(const int* __restrict__ deg,
                                                 int* __restrict__ row_ptr,
                                                 int* __restrict__ pos, int n) {
    __shared__ int sums[1024];
    int tid = threadIdx.x;
    int chunk = (n + 1023) / 1024;
    int base = tid * chunk;
    int s = 0;
    for (int i = 0; i < chunk; ++i) {
        int idx = base + i;
        if (idx < n) s += deg[idx];
    }
    sums[tid] = s;
    __syncthreads();
    for (int off = 1; off < 1024; off <<= 1) {
        int v = (tid >= off) ? sums[tid - off] : 0;
        __syncthreads();
        if (tid >= off) sums[tid] += v;
        __syncthreads();
    }
    int run = (tid == 0) ? 0 : sums[tid - 1];
    for (int i = 0; i < chunk; ++i) {
        int idx = base + i;
        if (idx < n) {
            row_ptr[idx] = run;
            pos[idx] = run;
            run += deg[idx];
            if (idx == n - 1) row_ptr[n] = run;
        }
    }
}

__global__ void csr_fill(const int* __restrict__ src, const int* __restrict__ dst,
                         int* __restrict__ pos, int* __restrict__ col, int n) {
    int i = blockIdx.x * blockDim.x + threadIdx.x;
    int stride = gridDim.x * blockDim.x;
    for (; i < n; i += stride) {
        int slot = atomicAdd(&pos[dst[i]], 1);
        col[slot] = src[i];
    }
}

// ---------------------------------------------------------------------------
// batched prep: z<6 weight transpose+convert; z==6 zero pooled/deg; z==7 x->bf16
__global__ __launch_bounds__(256) void transpose_all(
    const float* __restrict__ w1a, const float* __restrict__ w1b,
    const float* __restrict__ w2a, const float* __restrict__ w2b,
    const float* __restrict__ w3a, const float* __restrict__ w3b,
    __hip_bfloat16* __restrict__ o1a, __hip_bfloat16* __restrict__ o1b,
    __hip_bfloat16* __restrict__ o2a, __hip_bfloat16* __restrict__ o2b,
    __hip_bfloat16* __restrict__ o3a, __hip_bfloat16* __restrict__ o3b,
    int* __restrict__ zp, int zn,
    const float* __restrict__ x, __hip_bfloat16* __restrict__ x_bf, int n4)
{
    __shared__ float tile[32][33];
    int z = blockIdx.z;
    if (z == 6) {
        int i = (blockIdx.y * 8 + blockIdx.x) * 256 + threadIdx.x;
        for (; i < zn; i += 64 * 256) zp[i] = 0;
        return;
    }
    if (z == 7) {
        int i = (blockIdx.y * 8 + blockIdx.x) * 256 + threadIdx.x;
        for (; i < n4; i += 64 * 256) {
            float4 v = reinterpret_cast<const float4*>(x)[i];
            ushort4 u;
            u.x = f2bf(v.x); u.y = f2bf(v.y); u.z = f2bf(v.z); u.w = f2bf(v.w);
            reinterpret_cast<ushort4*>(x_bf)[i] = u;
        }
        return;
    }
    const float* in = (z == 0) ? w1a : (z == 1) ? w1b : (z == 2) ? w2a
                    : (z == 3) ? w2b : (z == 4) ? w3a : w3b;
    __hip_bfloat16* out = (z == 0) ? o1a : (z == 1) ? o1b : (z == 2) ? o2a
                        : (z == 3) ? o2b : (z == 4) ? o3a : o3b;
    int rows = (z == 0) ? IN_DIM : HID;
    int r0 = blockIdx.y * 32;
    if (r0 >= rows) return;
    int c0 = blockIdx.x * 32;
    int tx = threadIdx.x & 31, ty = threadIdx.x >> 5;
    for (int i = ty; i < 32; i += 8)
        tile[i][tx] = in[(size_t)(r0 + i) * HID + c0 + tx];
    __syncthreads();
    for (int i = ty; i < 32; i += 8)
        out[(size_t)(c0 + i) * rows + r0 + tx] = __float2bfloat16(tile[tx][i]);
}

// ---------------------------------------------------------------------------
// layer-1 gather (bf16, D=128): one wave per node, ushort2/lane, 8-deep unroll
__global__ __launch_bounds__(256) void gin_agg128(
    const __hip_bfloat16* __restrict__ X, const int* __restrict__ row_ptr,
    const int* __restrict__ col, __hip_bfloat16* __restrict__ out)
{
    int node = blockIdx.x * 4 + (threadIdx.x >> 6);
    if (node >= N_NODES) return;
    int lane = threadIdx.x & 63;
    int off = lane * 2;
    float a0, a1;
    {
        ushort2 v = *reinterpret_cast<const ushort2*>(X + (size_t)node * 128 + off);
        a0 = bf2f(v.x); a1 = bf2f(v.y);
    }
    int s = row_ptr[node], e = row_ptr[node + 1];
    int k = s;
    for (; k + 8 <= e; k += 8) {
        ushort2 u[8];
        #pragma unroll
        for (int j = 0; j < 8; ++j)
            u[j] = *reinterpret_cast<const ushort2*>(X + (size_t)col[k + j] * 128 + off);
        #pragma unroll
        for (int j = 0; j < 8; ++j) { a0 += bf2f(u[j].x); a1 += bf2f(u[j].y); }
    }
    for (; k < e; ++k) {
        ushort2 u = *reinterpret_cast<const ushort2*>(X + (size_t)col[k] * 128 + off);
        a0 += bf2f(u.x); a1 += bf2f(u.y);
    }
    ushort2 o;
    o.x = f2bf(a0); o.y = f2bf(a1);
    *reinterpret_cast<ushort2*>(out + (size_t)node * 128 + off) = o;
}

// gather (fp8 e4m3 input, D=256): one wave per node, 4 fp8 (uint)/lane, 8-deep.
// accumulate f32, emit bf16.
__global__ __launch_bounds__(256) void gin_agg256_f8(
    const unsigned char* __restrict__ X8, const int* __restrict__ row_ptr,
    const int* __restrict__ col, __hip_bfloat16* __restrict__ out)
{
    int node = blockIdx.x * 4 + (threadIdx.x >> 6);
    if (node >= N_NODES) return;
    int lane = threadIdx.x & 63;
    int boff = lane * 4;                 // 4 dims = 4 bytes

    float a0, a1, a2, a3;
    {
        unsigned int w = *reinterpret_cast<const unsigned int*>(X8 + (size_t)node * 256 + boff);
        f32x2 lo = __builtin_amdgcn_cvt_pk_f32_fp8(w, false);
        f32x2 hi = __builtin_amdgcn_cvt_pk_f32_fp8(w, true);
        a0 = lo.x; a1 = lo.y; a2 = hi.x; a3 = hi.y;
    }
    int s = row_ptr[node], e = row_ptr[node + 1];
    int k = s;
    for (; k + 8 <= e; k += 8) {
        unsigned int w[8];
        #pragma unroll
        for (int j = 0; j < 8; ++j)
            w[j] = *reinterpret_cast<const unsigned int*>(X8 + (size_t)col[k + j] * 256 + boff);
        #pragma unroll
        for (int j = 0; j < 8; ++j) {
            f32x2 lo = __builtin_amdgcn_cvt_pk_f32_fp8(w[j], false);
            f32x2 hi = __builtin_amdgcn_cvt_pk_f32_fp8(w[j], true);
            a0 += lo.x; a1 += lo.y; a2 += hi.x; a3 += hi.y;
        }
    }
    for (; k < e; ++k) {
        unsigned int w = *reinterpret_cast<const unsigned int*>(X8 + (size_t)col[k] * 256 + boff);
        f32x2 lo = __builtin_amdgcn_cvt_pk_f32_fp8(w, false);
        f32x2 hi = __builtin_amdgcn_cvt_pk_f32_fp8(w, true);
        a0 += lo.x; a1 += lo.y; a2 += hi.x; a3 += hi.y;
    }
    ushort4 o;
    o.x = f2bf(a0); o.y = f2bf(a1); o.z = f2bf(a2); o.w = f2bf(a3);
    *reinterpret_cast<ushort4*>((unsigned short*)out + (size_t)node * 256 + boff) = o;
}

// ---------------------------------------------------------------------------
// fused per-layer MLP: out = relu(relu(A @ W1t^T + b1) @ W2t^T + b2)
// BM=64, BN=256; 4 waves; plain-__syncthreads double-buffered gload_lds staging.
// FP8OUT=1 -> write fp8 e4m3 to C8; else bf16 to C.
template<int K1, int FP8OUT>
__global__ __launch_bounds__(256) void gin_mlp(
    const __hip_bfloat16* __restrict__ A, const __hip_bfloat16* __restrict__ W1t,
    const float* __restrict__ b1, const __hip_bfloat16* __restrict__ W2t,
    const float* __restrict__ b2, __hip_bfloat16* __restrict__ C,
    unsigned char* __restrict__ C8)
{
    __shared__ int4 smem4[4608];       // 73728 B
    char* smem = (char*)smem4;
    char* mid = smem + 40960;          // 64 x 512B

    int tid = threadIdx.x;
    int lane = tid & 63;
    int wid = tid >> 6;                // wave -> col slice
    int m0 = blockIdx.x * 64;

    int r16 = lane & 15;
    int g = lane >> 4;
    int gg = g ^ ((r16 >> 1) & 3);     // read-side chunk swizzle (64B-row tiles)

    int rseg = lane >> 2;
    int sw = (lane & 3) ^ ((lane >> 3) & 3);
    int rA = wid * 16 + rseg;

    const char* gA = (const char*)A + (size_t)(m0 + rA) * (K1 * 2) + sw * 16;
    const char* gW1[4];
    #pragma unroll
    for (int j = 0; j < 4; ++j) {
        int rW = (wid + 4 * j) * 16 + rseg;
        gW1[j] = (const char*)W1t + (size_t)rW * (K1 * 2) + sw * 16;
    }

    auto stage1 = [&](int buf, int t) {
        char* l = smem + buf * 20480;
        gl16(gA + t * 64, l + wid * 1024);
        #pragma unroll
        for (int j = 0; j < 4; ++j)
            gl16(gW1[j] + t * 64, l + 4096 + (wid + 4 * j) * 1024);
    };

    // ---- stage 1 ----
    f32x4 acc[4][4] = {};
    constexpr int NT1 = K1 / 32;

    stage1(0, 0);
    __syncthreads();
    #pragma unroll
    for (int t = 0; t < NT1; ++t) {
        int cur = t & 1;
        if (t + 1 < NT1) stage1(cur ^ 1, t + 1);
        const char* As = smem + cur * 20480;
        const char* Bs = As + 4096;
        bf16x8 af[4], bfv[4];
        #pragma unroll
        for (int m = 0; m < 4; ++m)
            af[m] = *reinterpret_cast<const bf16x8*>(As + (m * 16 + r16) * 64 + gg * 16);
        #pragma unroll
        for (int n = 0; n < 4; ++n)
            bfv[n] = *reinterpret_cast<const bf16x8*>(Bs + (wid * 64 + n * 16 + r16) * 64 + gg * 16);
        #pragma unroll
        for (int m = 0; m < 4; ++m)
            #pragma unroll
            for (int n = 0; n < 4; ++n)
                acc[m][n] = __builtin_amdgcn_mfma_f32_16x16x32_bf16(af[m], bfv[n], acc[m][n], 0, 0, 0);
        __syncthreads();
    }

    // issue W2 tile 0 early
    const char* gW2[4];
    #pragma unroll
    for (int j = 0; j < 4; ++j) {
        int rW = (wid + 4 * j) * 16 + rseg;
        gW2[j] = (const char*)W2t + (size_t)rW * 512 + sw * 16;
    }
    auto stageW2 = [&](int buf, int t) {
        char* l = smem + buf * 16384;
        #pragma unroll
        for (int j = 0; j < 4; ++j)
            gl16(gW2[j] + t * 64, l + (wid + 4 * j) * 1024);
    };
    stageW2(0, 0);

    // epilogue 1: bias+relu -> bf16 -> mid (swizzled). C/D: col=lane&15, row=g*4+reg
    #pragma unroll
    for (int m = 0; m < 4; ++m) {
        #pragma unroll
        for (int n = 0; n < 4; ++n) {
            int colX = wid * 64 + n * 16 + r16;
            float bb = b1[colX];
            int cb = colX >> 3;
            int within = (colX & 7) * 2;
            #pragma unroll
            for (int r = 0; r < 4; ++r) {
                int row = m * 16 + g * 4 + r;
                float v = fmaxf(acc[m][n][r] + bb, 0.f);
                *reinterpret_cast<unsigned short*>(
                    mid + row * 512 + ((cb ^ (row & 7)) << 4) + within) = f2bf(v);
            }
        }
    }

    __syncthreads();   // W2 tile0 ready, mid visible

    // ---- stage 2 ----
    f32x4 acc2[4][4] = {};
    #pragma unroll
    for (int t = 0; t < 8; ++t) {
        int cur = t & 1;
        if (t + 1 < 8) stageW2(cur ^ 1, t + 1);
        const char* Bs = smem + cur * 16384;
        bf16x8 af[4], bfv[4];
        #pragma unroll
        for (int m = 0; m < 4; ++m) {
            int row = m * 16 + r16;
            int c = (t * 4 + g) ^ (row & 7);
            af[m] = *reinterpret_cast<const bf16x8*>(mid + row * 512 + c * 16);
        }
        #pragma unroll
        for (int n = 0; n < 4; ++n)
            bfv[n] = *reinterpret_cast<const bf16x8*>(Bs + (wid * 64 + n * 16 + r16) * 64 + gg * 16);
        #pragma unroll
        for (int m = 0; m < 4; ++m)
            #pragma unroll
            for (int n = 0; n < 4; ++n)
                acc2[m][n] = __builtin_amdgcn_mfma_f32_16x16x32_bf16(af[m], bfv[n], acc2[m][n], 0, 0, 0);
        __syncthreads();
    }

    // epilogue 2: bias+relu -> fp8 or bf16
    #pragma unroll
    for (int m = 0; m < 4; ++m) {
        #pragma unroll
        for (int n = 0; n < 4; ++n) {
            int colX = wid * 64 + n * 16 + r16;
            float bb = b2[colX];
            #pragma unroll
            for (int r = 0; r < 4; ++r) {
                int row = m0 + m * 16 + g * 4 + r;
                float v = fmaxf(acc2[m][n][r] + bb, 0.f);
                if constexpr (FP8OUT) {
                    int b = __builtin_amdgcn_cvt_pk_fp8_f32(v, 0.f, 0, false);
                    C8[(size_t)row * HID + colX] = (unsigned char)(b & 0xff);
                } else {
                    C[(size_t)row * HID + colX] = __float2bfloat16(v);
                }
            }
        }
    }
}

// ---------------------------------------------------------------------------
// pooling: per-block register acc over 128 sorted nodes, atomic flush at
// graph boundaries. pooled zeroed by transpose_all z=6.
__global__ __launch_bounds__(256) void pool_partial(
    const __hip_bfloat16* __restrict__ h, const int* __restrict__ batch,
    float* __restrict__ pooled)
{
    __shared__ int sb[128];
    int n0 = blockIdx.x * 128;
    int cnt = N_NODES - n0; if (cnt > 128) cnt = 128;
    int d = threadIdx.x;
    if (d < cnt) sb[d] = batch[n0 + d];
    __syncthreads();
    float acc = 0.f;
    int cur = sb[0];
    for (int i = 0; i < cnt; ++i) {
        int g = sb[i];
        if (g != cur) { atomicAdd(&pooled[cur * HID + d], acc); acc = 0.f; cur = g; }
        acc += bf2f(*reinterpret_cast<const unsigned short*>(h + (size_t)(n0 + i) * HID + d));
    }
    atomicAdd(&pooled[cur * HID + d], acc);
}

// head: logits = pooled @ wl + bl ; log_softmax
__global__ __launch_bounds__(256) void head_kernel(
    const float* __restrict__ pooled, const float* __restrict__ wl,
    const float* __restrict__ bl, float* __restrict__ out)
{
    int gph = blockIdx.x;
    int d = threadIdx.x;
    __shared__ float p[HID];
    __shared__ float logits[OUT_DIM];
    __shared__ float lse_s;
    p[d] = pooled[gph * HID + d];
    __syncthreads();
    if (d < OUT_DIM) {
        float v = bl[d];
        for (int k = 0; k < HID; ++k) v += p[k] * wl[k * OUT_DIM + d];
        logits[d] = v;
    }
    __syncthreads();
    if (d == 0) {
        float mx = logits[0];
        for (int j = 1; j < OUT_DIM; ++j) mx = fmaxf(mx, logits[j]);
        float s = 0.f;
        for (int j = 0; j < OUT_DIM; ++j) s += expf(logits[j] - mx);
        lse_s = mx + logf(s);
    }
    __syncthreads();
    if (d < OUT_DIM) out[gph * OUT_DIM + d] = logits[d] - lse_s;
}

// ---------------------------------------------------------------------------
extern "C" void kernel_launch(void* const* d_in, const int* in_sizes, int n_in,
                              void* d_out, int out_size, void* d_ws, size_t ws_size,
                              hipStream_t stream) {
    const float* x    = (const float*)d_in[0];
    const int*   ei   = (const int*)d_in[1];
    const int*   batch= (const int*)d_in[2];
    const float* w1a  = (const float*)d_in[3];
    const float* b1a  = (const float*)d_in[4];
    const float* w1b  = (const float*)d_in[5];
    const float* b1b  = (const float*)d_in[6];
    const float* w2a  = (const float*)d_in[7];
    const float* b2a  = (const float*)d_in[8];
    const float* w2b  = (const float*)d_in[9];
    const float* b2b  = (const float*)d_in[10];
    const float* w3a  = (const float*)d_in[11];
    const float* b3a  = (const float*)d_in[12];
    const float* w3b  = (const float*)d_in[13];
    const float* b3b  = (const float*)d_in[14];
    const float* wl   = (const float*)d_in[15];
    const float* bl   = (const float*)d_in[16];

    const int* src = ei;
    const int* dst = ei + N_EDGES;

    __hip_bfloat16* bufA = (__hip_bfloat16*)d_ws;                  // M_PAD*256 bf16
    __hip_bfloat16* bufB = bufA + (size_t)M_PAD * HID;             // M_PAD*256 bf16
    unsigned char*  h8   = (unsigned char*)(bufB + (size_t)M_PAD * HID); // M_PAD*256 fp8
    __hip_bfloat16* x_bf = (__hip_bfloat16*)(h8 + (size_t)M_PAD * HID);  // N_NODES*128
    __hip_bfloat16* wt1a = x_bf + (size_t)N_NODES * IN_DIM;        // 256*128
    __hip_bfloat16* wt1b = wt1a + HID * IN_DIM;                    // 256*256
    __hip_bfloat16* wt2a = wt1b + HID * HID;
    __hip_bfloat16* wt2b = wt2a + HID * HID;
    __hip_bfloat16* wt3a = wt2b + HID * HID;
    __hip_bfloat16* wt3b = wt3a + HID * HID;
    float* pooled = (float*)(wt3b + HID * HID);                    // 64*256
    int* deg     = (int*)(pooled + N_GRAPHS * HID);                // contiguous w/ pooled
    int* row_ptr = deg + N_NODES;
    int* pos     = row_ptr + (N_NODES + 1);
    int* col     = pos + N_NODES;                                  // N_EDGES

    float* out = (float*)d_out;

    // ---- prep: weights transpose, zero pooled/deg, x->bf16 (one kernel) ----
    int zn = N_GRAPHS * HID + N_NODES;
    int n4 = N_NODES * IN_DIM / 4;
    transpose_all<<<dim3(8, 8, 8), 256, 0, stream>>>(
        w1a, w1b, w2a, w2b, w3a, w3b, wt1a, wt1b, wt2a, wt2b, wt3a, wt3b,
        (int*)pooled, zn, x, x_bf, n4);

    degree_hist<<<(N_EDGES + 255) / 256, 256, 0, stream>>>(dst, deg, N_EDGES);
    scan_deg<<<1, 1024, 0, stream>>>(deg, row_ptr, pos, N_NODES);
    csr_fill<<<(N_EDGES + 255) / 256, 256, 0, stream>>>(src, dst, pos, col, N_EDGES);

    int agg_blocks = (N_NODES + 3) / 4;
    int mlp_blocks = M_PAD / 64;

    // ---- layer 1: bf16 gather, MLP -> fp8 h ----
    gin_agg128<<<agg_blocks, 256, 0, stream>>>(x_bf, row_ptr, col, bufA);
    gin_mlp<IN_DIM, 1><<<mlp_blocks, 256, 0, stream>>>(bufA, wt1a, b1a, wt1b, b1b, bufB, h8);

    // ---- layer 2: fp8 gather, MLP -> fp8 h ----
    gin_agg256_f8<<<agg_blocks, 256, 0, stream>>>(h8, row_ptr, col, bufA);
    gin_mlp<HID, 1><<<mlp_blocks, 256, 0, stream>>>(bufA, wt2a, b2a, wt2b, b2b, bufB, h8);

    // ---- layer 3: fp8 gather, MLP -> bf16 h ----
    gin_agg256_f8<<<agg_blocks, 256, 0, stream>>>(h8, row_ptr, col, bufA);
    gin_mlp<HID, 0><<<mlp_blocks, 256, 0, stream>>>(bufA, wt3a, b3a, wt3b, b3b, bufB, h8);

    // ---- pool + head ----
    pool_partial<<<(N_NODES + 127) / 128, 256, 0, stream>>>(bufB, batch, pooled);
    head_kernel<<<N_GRAPHS, 256, 0, stream>>>(pooled, wl, bl, out);
}

// Round 10
// 220.812 us; speedup vs baseline: 1.5826x; 1.0241x over previous
//
#include <hip/hip_runtime.h>
#include <hip/hip_bf16.h>

#define N_NODES 20000
#define M_PAD 20096            // 314 * 64
#define IN_DIM 128
#define HID 256
#define OUT_DIM 10
#define N_EDGES 320000
#define N_GRAPHS 64

typedef __attribute__((ext_vector_type(8))) short bf16x8;
typedef __attribute__((ext_vector_type(4))) float f32x4;
typedef __attribute__((ext_vector_type(2))) float f32x2;

__device__ inline float bf2f(unsigned short u) {
    return __uint_as_float((unsigned int)u << 16);
}
__device__ inline unsigned short f2bf(float f) {
    __hip_bfloat16 h = __float2bfloat16(f);
    return *reinterpret_cast<unsigned short*>(&h);
}

__device__ __forceinline__ void gl16(const void* g, void* l) {
    __builtin_amdgcn_global_load_lds(
        (const __attribute__((address_space(1))) unsigned int*)g,
        (__attribute__((address_space(3))) unsigned int*)l, 16, 0, 0);
}

// ---------------------------------------------------------------------------
// CSR build (deg zeroed by hipMemsetAsync; histogram fused into transpose_all)
__global__ __launch_bounds__(1024) void scan_deg(const int* __restrict__ deg,
                                                 int* __restrict__ row_ptr,
                                                 int* __restrict__ pos, int n) {
    __shared__ int sums[1024];
    int tid = threadIdx.x;
    int chunk = (n + 1023) / 1024;
    int base = tid * chunk;
    int s = 0;
    for (int i = 0; i < chunk; ++i) {
        int idx = base + i;
        if (idx < n) s += deg[idx];
    }
    sums[tid] = s;
    __syncthreads();
    for (int off = 1; off < 1024; off <<= 1) {
        int v = (tid >= off) ? sums[tid - off] : 0;
        __syncthreads();
        if (tid >= off) sums[tid] += v;
        __syncthreads();
    }
    int run = (tid == 0) ? 0 : sums[tid - 1];
    for (int i = 0; i < chunk; ++i) {
        int idx = base + i;
        if (idx < n) {
            row_ptr[idx] = run;
            pos[idx] = run;
            run += deg[idx];
            if (idx == n - 1) row_ptr[n] = run;
        }
    }
}

__global__ void csr_fill(const int* __restrict__ src, const int* __restrict__ dst,
                         int* __restrict__ pos, int* __restrict__ col, int n) {
    int i = blockIdx.x * blockDim.x + threadIdx.x;
    int stride = gridDim.x * blockDim.x;
    for (; i < n; i += stride) {
        int slot = atomicAdd(&pos[dst[i]], 1);
        col[slot] = src[i];
    }
}

// ---------------------------------------------------------------------------
// batched prep: z<6 weight transpose+convert; z==6 x->fp8; z==7 degree_hist
__global__ __launch_bounds__(256) void transpose_all(
    const float* __restrict__ w1a, const float* __restrict__ w1b,
    const float* __restrict__ w2a, const float* __restrict__ w2b,
    const float* __restrict__ w3a, const float* __restrict__ w3b,
    __hip_bfloat16* __restrict__ o1a, __hip_bfloat16* __restrict__ o1b,
    __hip_bfloat16* __restrict__ o2a, __hip_bfloat16* __restrict__ o2b,
    __hip_bfloat16* __restrict__ o3a, __hip_bfloat16* __restrict__ o3b,
    const float* __restrict__ x, unsigned char* __restrict__ x_f8, int n4,
    const int* __restrict__ dst, int* __restrict__ deg)
{
    __shared__ float tile[32][33];
    int z = blockIdx.z;
    if (z == 6) {
        int i = (blockIdx.y * 8 + blockIdx.x) * 256 + threadIdx.x;
        for (; i < n4; i += 64 * 256) {
            float4 v = reinterpret_cast<const float4*>(x)[i];
            int w = __builtin_amdgcn_cvt_pk_fp8_f32(v.x, v.y, 0, false);
            w = __builtin_amdgcn_cvt_pk_fp8_f32(v.z, v.w, w, true);
            reinterpret_cast<unsigned int*>(x_f8)[i] = (unsigned int)w;
        }
        return;
    }
    if (z == 7) {
        int i = (blockIdx.y * 8 + blockIdx.x) * 256 + threadIdx.x;
        for (; i < N_EDGES; i += 64 * 256) atomicAdd(&deg[dst[i]], 1);
        return;
    }
    const float* in = (z == 0) ? w1a : (z == 1) ? w1b : (z == 2) ? w2a
                    : (z == 3) ? w2b : (z == 4) ? w3a : w3b;
    __hip_bfloat16* out = (z == 0) ? o1a : (z == 1) ? o1b : (z == 2) ? o2a
                        : (z == 3) ? o2b : (z == 4) ? o3a : o3b;
    int rows = (z == 0) ? IN_DIM : HID;
    int r0 = blockIdx.y * 32;
    if (r0 >= rows) return;
    int c0 = blockIdx.x * 32;
    int tx = threadIdx.x & 31, ty = threadIdx.x >> 5;
    for (int i = ty; i < 32; i += 8)
        tile[i][tx] = in[(size_t)(r0 + i) * HID + c0 + tx];
    __syncthreads();
    for (int i = ty; i < 32; i += 8)
        out[(size_t)(c0 + i) * rows + r0 + tx] = __float2bfloat16(tile[tx][i]);
}

// ---------------------------------------------------------------------------
// fp8 gather-aggregate: out_bf16[i] = x[i] + sum_{j in in-edges(i)} x[j]
// one wave per node; D=256 -> 4 B/lane, D=128 -> 2 B/lane; 8-deep unroll.
template<int D>
__global__ __launch_bounds__(256) void gin_agg_f8(
    const unsigned char* __restrict__ X8, const int* __restrict__ row_ptr,
    const int* __restrict__ col, __hip_bfloat16* __restrict__ out)
{
    int node = blockIdx.x * 4 + (threadIdx.x >> 6);
    if (node >= N_NODES) return;
    int lane = threadIdx.x & 63;
    constexpr int BPL = D / 64;        // bytes (=dims) per lane: 4 or 2
    int boff = lane * BPL;

    float a0 = 0.f, a1 = 0.f, a2 = 0.f, a3 = 0.f;
    {
        const unsigned char* p = X8 + (size_t)node * D + boff;
        unsigned int w = (BPL == 4) ? *reinterpret_cast<const unsigned int*>(p)
                                    : (unsigned int)*reinterpret_cast<const unsigned short*>(p);
        f32x2 lo = __builtin_amdgcn_cvt_pk_f32_fp8(w, false);
        a0 = lo.x; a1 = lo.y;
        if constexpr (BPL == 4) {
            f32x2 hi = __builtin_amdgcn_cvt_pk_f32_fp8(w, true);
            a2 = hi.x; a3 = hi.y;
        }
    }
    int s = row_ptr[node], e = row_ptr[node + 1];
    int k = s;
    for (; k + 8 <= e; k += 8) {
        unsigned int w[8];
        #pragma unroll
        for (int j = 0; j < 8; ++j) {
            const unsigned char* p = X8 + (size_t)col[k + j] * D + boff;
            w[j] = (BPL == 4) ? *reinterpret_cast<const unsigned int*>(p)
                              : (unsigned int)*reinterpret_cast<const unsigned short*>(p);
        }
        #pragma unroll
        for (int j = 0; j < 8; ++j) {
            f32x2 lo = __builtin_amdgcn_cvt_pk_f32_fp8(w[j], false);
            a0 += lo.x; a1 += lo.y;
            if constexpr (BPL == 4) {
                f32x2 hi = __builtin_amdgcn_cvt_pk_f32_fp8(w[j], true);
                a2 += hi.x; a3 += hi.y;
            }
        }
    }
    for (; k < e; ++k) {
        const unsigned char* p = X8 + (size_t)col[k] * D + boff;
        unsigned int w = (BPL == 4) ? *reinterpret_cast<const unsigned int*>(p)
                                    : (unsigned int)*reinterpret_cast<const unsigned short*>(p);
        f32x2 lo = __builtin_amdgcn_cvt_pk_f32_fp8(w, false);
        a0 += lo.x; a1 += lo.y;
        if constexpr (BPL == 4) {
            f32x2 hi = __builtin_amdgcn_cvt_pk_f32_fp8(w, true);
            a2 += hi.x; a3 += hi.y;
        }
    }
    unsigned short* op = (unsigned short*)out + (size_t)node * D + boff;
    if constexpr (BPL == 4) {
        ushort4 o;
        o.x = f2bf(a0); o.y = f2bf(a1); o.z = f2bf(a2); o.w = f2bf(a3);
        *reinterpret_cast<ushort4*>(op) = o;
    } else {
        ushort2 o;
        o.x = f2bf(a0); o.y = f2bf(a1);
        *reinterpret_cast<ushort2*>(op) = o;
    }
}

// ---------------------------------------------------------------------------
// fused per-layer MLP: out = relu(relu(A @ W1t^T + b1) @ W2t^T + b2)
// BM=64, BN=256; 4 waves; plain-__syncthreads double-buffered gload_lds staging.
// FP8OUT=1 -> write fp8 e4m3 to C8; else bf16 to C.
template<int K1, int FP8OUT>
__global__ __launch_bounds__(256) void gin_mlp(
    const __hip_bfloat16* __restrict__ A, const __hip_bfloat16* __restrict__ W1t,
    const float* __restrict__ b1, const __hip_bfloat16* __restrict__ W2t,
    const float* __restrict__ b2, __hip_bfloat16* __restrict__ C,
    unsigned char* __restrict__ C8)
{
    __shared__ int4 smem4[4608];       // 73728 B
    char* smem = (char*)smem4;
    char* mid = smem + 40960;          // 64 x 512B

    int tid = threadIdx.x;
    int lane = tid & 63;
    int wid = tid >> 6;                // wave -> col slice
    int m0 = blockIdx.x * 64;

    int r16 = lane & 15;
    int g = lane >> 4;
    int gg = g ^ ((r16 >> 1) & 3);     // read-side chunk swizzle (64B-row tiles)

    int rseg = lane >> 2;
    int sw = (lane & 3) ^ ((lane >> 3) & 3);
    int rA = wid * 16 + rseg;

    const char* gA = (const char*)A + (size_t)(m0 + rA) * (K1 * 2) + sw * 16;
    const char* gW1[4];
    #pragma unroll
    for (int j = 0; j < 4; ++j) {
        int rW = (wid + 4 * j) * 16 + rseg;
        gW1[j] = (const char*)W1t + (size_t)rW * (K1 * 2) + sw * 16;
    }

    auto stage1 = [&](int buf, int t) {
        char* l = smem + buf * 20480;
        gl16(gA + t * 64, l + wid * 1024);
        #pragma unroll
        for (int j = 0; j < 4; ++j)
            gl16(gW1[j] + t * 64, l + 4096 + (wid + 4 * j) * 1024);
    };

    // ---- stage 1 ----
    f32x4 acc[4][4] = {};
    constexpr int NT1 = K1 / 32;

    stage1(0, 0);
    __syncthreads();
    #pragma unroll
    for (int t = 0; t < NT1; ++t) {
        int cur = t & 1;
        if (t + 1 < NT1) stage1(cur ^ 1, t + 1);
        const char* As = smem + cur * 20480;
        const char* Bs = As + 4096;
        bf16x8 af[4], bfv[4];
        #pragma unroll
        for (int m = 0; m < 4; ++m)
            af[m] = *reinterpret_cast<const bf16x8*>(As + (m * 16 + r16) * 64 + gg * 16);
        #pragma unroll
        for (int n = 0; n < 4; ++n)
            bfv[n] = *reinterpret_cast<const bf16x8*>(Bs + (wid * 64 + n * 16 + r16) * 64 + gg * 16);
        #pragma unroll
        for (int m = 0; m < 4; ++m)
            #pragma unroll
            for (int n = 0; n < 4; ++n)
                acc[m][n] = __builtin_amdgcn_mfma_f32_16x16x32_bf16(af[m], bfv[n], acc[m][n], 0, 0, 0);
        __syncthreads();
    }

    // issue W2 tile 0 early
    const char* gW2[4];
    #pragma unroll
    for (int j = 0; j < 4; ++j) {
        int rW = (wid + 4 * j) * 16 + rseg;
        gW2[j] = (const char*)W2t + (size_t)rW * 512 + sw * 16;
    }
    auto stageW2 = [&](int buf, int t) {
        char* l = smem + buf * 16384;
        #pragma unroll
        for (int j = 0; j < 4; ++j)
            gl16(gW2[j] + t * 64, l + (wid + 4 * j) * 1024);
    };
    stageW2(0, 0);

    // epilogue 1: bias+relu -> bf16 -> mid (swizzled). C/D: col=lane&15, row=g*4+reg
    #pragma unroll
    for (int m = 0; m < 4; ++m) {
        #pragma unroll
        for (int n = 0; n < 4; ++n) {
            int colX = wid * 64 + n * 16 + r16;
            float bb = b1[colX];
            int cb = colX >> 3;
            int within = (colX & 7) * 2;
            #pragma unroll
            for (int r = 0; r < 4; ++r) {
                int row = m * 16 + g * 4 + r;
                float v = fmaxf(acc[m][n][r] + bb, 0.f);
                *reinterpret_cast<unsigned short*>(
                    mid + row * 512 + ((cb ^ (row & 7)) << 4) + within) = f2bf(v);
            }
        }
    }

    __syncthreads();   // W2 tile0 ready, mid visible

    // ---- stage 2 ----
    f32x4 acc2[4][4] = {};
    #pragma unroll
    for (int t = 0; t < 8; ++t) {
        int cur = t & 1;
        if (t + 1 < 8) stageW2(cur ^ 1, t + 1);
        const char* Bs = smem + cur * 16384;
        bf16x8 af[4], bfv[4];
        #pragma unroll
        for (int m = 0; m < 4; ++m) {
            int row = m * 16 + r16;
            int c = (t * 4 + g) ^ (row & 7);
            af[m] = *reinterpret_cast<const bf16x8*>(mid + row * 512 + c * 16);
        }
        #pragma unroll
        for (int n = 0; n < 4; ++n)
            bfv[n] = *reinterpret_cast<const bf16x8*>(Bs + (wid * 64 + n * 16 + r16) * 64 + gg * 16);
        #pragma unroll
        for (int m = 0; m < 4; ++m)
            #pragma unroll
            for (int n = 0; n < 4; ++n)
                acc2[m][n] = __builtin_amdgcn_mfma_f32_16x16x32_bf16(af[m], bfv[n], acc2[m][n], 0, 0, 0);
        __syncthreads();
    }

    // epilogue 2: bias+relu -> fp8 or bf16
    #pragma unroll
    for (int m = 0; m < 4; ++m) {
        #pragma unroll
        for (int n = 0; n < 4; ++n) {
            int colX = wid * 64 + n * 16 + r16;
            float bb = b2[colX];
            #pragma unroll
            for (int r = 0; r < 4; ++r) {
                int row = m0 + m * 16 + g * 4 + r;
                float v = fmaxf(acc2[m][n][r] + bb, 0.f);
                if constexpr (FP8OUT) {
                    int b = __builtin_amdgcn_cvt_pk_fp8_f32(v, 0.f, 0, false);
                    C8[(size_t)row * HID + colX] = (unsigned char)(b & 0xff);
                } else {
                    C[(size_t)row * HID + colX] = __float2bfloat16(v);
                }
            }
        }
    }
}

// ---------------------------------------------------------------------------
// pooling: per-block register acc over 128 sorted nodes, atomic flush at
// graph boundaries. pooled zeroed by hipMemsetAsync.
__global__ __launch_bounds__(256) void pool_partial(
    const __hip_bfloat16* __restrict__ h, const int* __restrict__ batch,
    float* __restrict__ pooled)
{
    __shared__ int sb[128];
    int n0 = blockIdx.x * 128;
    int cnt = N_NODES - n0; if (cnt > 128) cnt = 128;
    int d = threadIdx.x;
    if (d < cnt) sb[d] = batch[n0 + d];
    __syncthreads();
    float acc = 0.f;
    int cur = sb[0];
    for (int i = 0; i < cnt; ++i) {
        int g = sb[i];
        if (g != cur) { atomicAdd(&pooled[cur * HID + d], acc); acc = 0.f; cur = g; }
        acc += bf2f(*reinterpret_cast<const unsigned short*>(h + (size_t)(n0 + i) * HID + d));
    }
    atomicAdd(&pooled[cur * HID + d], acc);
}

// head: logits = pooled @ wl + bl ; log_softmax
__global__ __launch_bounds__(256) void head_kernel(
    const float* __restrict__ pooled, const float* __restrict__ wl,
    const float* __restrict__ bl, float* __restrict__ out)
{
    int gph = blockIdx.x;
    int d = threadIdx.x;
    __shared__ float p[HID];
    __shared__ float logits[OUT_DIM];
    __shared__ float lse_s;
    p[d] = pooled[gph * HID + d];
    __syncthreads();
    if (d < OUT_DIM) {
        float v = bl[d];
        for (int k = 0; k < HID; ++k) v += p[k] * wl[k * OUT_DIM + d];
        logits[d] = v;
    }
    __syncthreads();
    if (d == 0) {
        float mx = logits[0];
        for (int j = 1; j < OUT_DIM; ++j) mx = fmaxf(mx, logits[j]);
        float s = 0.f;
        for (int j = 0; j < OUT_DIM; ++j) s += expf(logits[j] - mx);
        lse_s = mx + logf(s);
    }
    __syncthreads();
    if (d < OUT_DIM) out[gph * OUT_DIM + d] = logits[d] - lse_s;
}

// ---------------------------------------------------------------------------
extern "C" void kernel_launch(void* const* d_in, const int* in_sizes, int n_in,
                              void* d_out, int out_size, void* d_ws, size_t ws_size,
                              hipStream_t stream) {
    const float* x    = (const float*)d_in[0];
    const int*   ei   = (const int*)d_in[1];
    const int*   batch= (const int*)d_in[2];
    const float* w1a  = (const float*)d_in[3];
    const float* b1a  = (const float*)d_in[4];
    const float* w1b  = (const float*)d_in[5];
    const float* b1b  = (const float*)d_in[6];
    const float* w2a  = (const float*)d_in[7];
    const float* b2a  = (const float*)d_in[8];
    const float* w2b  = (const float*)d_in[9];
    const float* b2b  = (const float*)d_in[10];
    const float* w3a  = (const float*)d_in[11];
    const float* b3a  = (const float*)d_in[12];
    const float* w3b  = (const float*)d_in[13];
    const float* b3b  = (const float*)d_in[14];
    const float* wl   = (const float*)d_in[15];
    const float* bl   = (const float*)d_in[16];

    const int* src = ei;
    const int* dst = ei + N_EDGES;

    __hip_bfloat16* bufA = (__hip_bfloat16*)d_ws;                  // M_PAD*256 bf16
    __hip_bfloat16* bufB = bufA + (size_t)M_PAD * HID;             // M_PAD*256 bf16
    unsigned char*  h8   = (unsigned char*)(bufB + (size_t)M_PAD * HID); // M_PAD*256 fp8
    unsigned char*  x_f8 = h8 + (size_t)M_PAD * HID;               // N_NODES*128 fp8
    __hip_bfloat16* wt1a = (__hip_bfloat16*)(x_f8 + (size_t)N_NODES * IN_DIM);
    __hip_bfloat16* wt1b = wt1a + HID * IN_DIM;                    // 256*256
    __hip_bfloat16* wt2a = wt1b + HID * HID;
    __hip_bfloat16* wt2b = wt2a + HID * HID;
    __hip_bfloat16* wt3a = wt2b + HID * HID;
    __hip_bfloat16* wt3b = wt3a + HID * HID;
    float* pooled = (float*)(wt3b + HID * HID);                    // 64*256
    int* deg     = (int*)(pooled + N_GRAPHS * HID);                // contiguous w/ pooled
    int* row_ptr = deg + N_NODES;
    int* pos     = row_ptr + (N_NODES + 1);
    int* col     = pos + N_NODES;                                  // N_EDGES

    float* out = (float*)d_out;

    // ---- prep: zero pooled+deg (one memset), then fused transpose/x-fp8/hist ----
    hipMemsetAsync(pooled, 0,
                   (size_t)N_GRAPHS * HID * sizeof(float) + (size_t)N_NODES * sizeof(int),
                   stream);
    int n4 = N_NODES * IN_DIM / 4;
    transpose_all<<<dim3(8, 8, 8), 256, 0, stream>>>(
        w1a, w1b, w2a, w2b, w3a, w3b, wt1a, wt1b, wt2a, wt2b, wt3a, wt3b,
        x, x_f8, n4, dst, deg);

    scan_deg<<<1, 1024, 0, stream>>>(deg, row_ptr, pos, N_NODES);
    csr_fill<<<(N_EDGES + 255) / 256, 256, 0, stream>>>(src, dst, pos, col, N_EDGES);

    int agg_blocks = (N_NODES + 3) / 4;
    int mlp_blocks = M_PAD / 64;

    // ---- layer 1: fp8 gather, MLP -> fp8 h ----
    gin_agg_f8<IN_DIM><<<agg_blocks, 256, 0, stream>>>(x_f8, row_ptr, col, bufA);
    gin_mlp<IN_DIM, 1><<<mlp_blocks, 256, 0, stream>>>(bufA, wt1a, b1a, wt1b, b1b, bufB, h8);

    // ---- layer 2: fp8 gather, MLP -> fp8 h ----
    gin_agg_f8<HID><<<agg_blocks, 256, 0, stream>>>(h8, row_ptr, col, bufA);
    gin_mlp<HID, 1><<<mlp_blocks, 256, 0, stream>>>(bufA, wt2a, b2a, wt2b, b2b, bufB, h8);

    // ---- layer 3: fp8 gather, MLP -> bf16 h ----
    gin_agg_f8<HID><<<agg_blocks, 256, 0, stream>>>(h8, row_ptr, col, bufA);
    gin_mlp<HID, 0><<<mlp_blocks, 256, 0, stream>>>(bufA, wt3a, b3a, wt3b, b3b, bufB, h8);

    // ---- pool + head ----
    pool_partial<<<(N_NODES + 127) / 128, 256, 0, stream>>>(bufB, batch, pooled);
    head_kernel<<<N_GRAPHS, 256, 0, stream>>>(pooled, wl, bl, out);
}

// Round 11
// 219.966 us; speedup vs baseline: 1.5887x; 1.0038x over previous
//
#include <hip/hip_runtime.h>
#include <hip/hip_bf16.h>

#define N_NODES 20000
#define M_PAD 20096            // 314 * 64
#define IN_DIM 128
#define HID 256
#define OUT_DIM 10
#define N_EDGES 320000
#define N_GRAPHS 64

typedef __attribute__((ext_vector_type(8))) short bf16x8;
typedef __attribute__((ext_vector_type(4))) float f32x4;
typedef __attribute__((ext_vector_type(2))) float f32x2;

__device__ inline float bf2f(unsigned short u) {
    return __uint_as_float((unsigned int)u << 16);
}
__device__ inline unsigned short f2bf(float f) {
    __hip_bfloat16 h = __float2bfloat16(f);
    return *reinterpret_cast<unsigned short*>(&h);
}

__device__ __forceinline__ void gl16(const void* g, void* l) {
    __builtin_amdgcn_global_load_lds(
        (const __attribute__((address_space(1))) unsigned int*)g,
        (__attribute__((address_space(3))) unsigned int*)l, 16, 0, 0);
}

// ---------------------------------------------------------------------------
// zero kernel (replaces pathological hipMemsetAsync fill: 43us -> ~2us)
__global__ void zero_int(int* __restrict__ p, int n) {
    int i = blockIdx.x * blockDim.x + threadIdx.x;
    if (i < n) p[i] = 0;
}

// ---------------------------------------------------------------------------
// CSR build (deg zeroed by zero_int; histogram fused into transpose_all)
__global__ __launch_bounds__(1024) void scan_deg(const int* __restrict__ deg,
                                                 int* __restrict__ row_ptr,
                                                 int* __restrict__ pos, int n) {
    __shared__ int sums[1024];
    int tid = threadIdx.x;
    int chunk = (n + 1023) / 1024;
    int base = tid * chunk;
    int s = 0;
    for (int i = 0; i < chunk; ++i) {
        int idx = base + i;
        if (idx < n) s += deg[idx];
    }
    sums[tid] = s;
    __syncthreads();
    for (int off = 1; off < 1024; off <<= 1) {
        int v = (tid >= off) ? sums[tid - off] : 0;
        __syncthreads();
        if (tid >= off) sums[tid] += v;
        __syncthreads();
    }
    int run = (tid == 0) ? 0 : sums[tid - 1];
    for (int i = 0; i < chunk; ++i) {
        int idx = base + i;
        if (idx < n) {
            row_ptr[idx] = run;
            pos[idx] = run;
            run += deg[idx];
            if (idx == n - 1) row_ptr[n] = run;
        }
    }
}

__global__ void csr_fill(const int* __restrict__ src, const int* __restrict__ dst,
                         int* __restrict__ pos, int* __restrict__ col, int n) {
    int i = blockIdx.x * blockDim.x + threadIdx.x;
    int stride = gridDim.x * blockDim.x;
    for (; i < n; i += stride) {
        int slot = atomicAdd(&pos[dst[i]], 1);
        col[slot] = src[i];
    }
}

// ---------------------------------------------------------------------------
// batched prep: z<6 weight transpose+convert; z==6 x->fp8; z==7 degree_hist
__global__ __launch_bounds__(256) void transpose_all(
    const float* __restrict__ w1a, const float* __restrict__ w1b,
    const float* __restrict__ w2a, const float* __restrict__ w2b,
    const float* __restrict__ w3a, const float* __restrict__ w3b,
    __hip_bfloat16* __restrict__ o1a, __hip_bfloat16* __restrict__ o1b,
    __hip_bfloat16* __restrict__ o2a, __hip_bfloat16* __restrict__ o2b,
    __hip_bfloat16* __restrict__ o3a, __hip_bfloat16* __restrict__ o3b,
    const float* __restrict__ x, unsigned char* __restrict__ x_f8, int n4,
    const int* __restrict__ dst, int* __restrict__ deg)
{
    __shared__ float tile[32][33];
    int z = blockIdx.z;
    if (z == 6) {
        int i = (blockIdx.y * 8 + blockIdx.x) * 256 + threadIdx.x;
        for (; i < n4; i += 64 * 256) {
            float4 v = reinterpret_cast<const float4*>(x)[i];
            int w = __builtin_amdgcn_cvt_pk_fp8_f32(v.x, v.y, 0, false);
            w = __builtin_amdgcn_cvt_pk_fp8_f32(v.z, v.w, w, true);
            reinterpret_cast<unsigned int*>(x_f8)[i] = (unsigned int)w;
        }
        return;
    }
    if (z == 7) {
        int i = (blockIdx.y * 8 + blockIdx.x) * 256 + threadIdx.x;
        for (; i < N_EDGES; i += 64 * 256) atomicAdd(&deg[dst[i]], 1);
        return;
    }
    const float* in = (z == 0) ? w1a : (z == 1) ? w1b : (z == 2) ? w2a
                    : (z == 3) ? w2b : (z == 4) ? w3a : w3b;
    __hip_bfloat16* out = (z == 0) ? o1a : (z == 1) ? o1b : (z == 2) ? o2a
                        : (z == 3) ? o2b : (z == 4) ? o3a : o3b;
    int rows = (z == 0) ? IN_DIM : HID;
    int r0 = blockIdx.y * 32;
    if (r0 >= rows) return;
    int c0 = blockIdx.x * 32;
    int tx = threadIdx.x & 31, ty = threadIdx.x >> 5;
    for (int i = ty; i < 32; i += 8)
        tile[i][tx] = in[(size_t)(r0 + i) * HID + c0 + tx];
    __syncthreads();
    for (int i = ty; i < 32; i += 8)
        out[(size_t)(c0 + i) * rows + r0 + tx] = __float2bfloat16(tile[tx][i]);
}

// ---------------------------------------------------------------------------
// fp8 gather-aggregate: out_bf16[i] = x[i] + sum_{j in in-edges(i)} x[j]
// one wave per node; D=256 -> 4 B/lane, D=128 -> 2 B/lane; 8-deep unroll.
template<int D>
__global__ __launch_bounds__(256) void gin_agg_f8(
    const unsigned char* __restrict__ X8, const int* __restrict__ row_ptr,
    const int* __restrict__ col, __hip_bfloat16* __restrict__ out)
{
    int node = blockIdx.x * 4 + (threadIdx.x >> 6);
    if (node >= N_NODES) return;
    int lane = threadIdx.x & 63;
    constexpr int BPL = D / 64;        // bytes (=dims) per lane: 4 or 2
    int boff = lane * BPL;

    float a0 = 0.f, a1 = 0.f, a2 = 0.f, a3 = 0.f;
    {
        const unsigned char* p = X8 + (size_t)node * D + boff;
        unsigned int w = (BPL == 4) ? *reinterpret_cast<const unsigned int*>(p)
                                    : (unsigned int)*reinterpret_cast<const unsigned short*>(p);
        f32x2 lo = __builtin_amdgcn_cvt_pk_f32_fp8(w, false);
        a0 = lo.x; a1 = lo.y;
        if constexpr (BPL == 4) {
            f32x2 hi = __builtin_amdgcn_cvt_pk_f32_fp8(w, true);
            a2 = hi.x; a3 = hi.y;
        }
    }
    int s = row_ptr[node], e = row_ptr[node + 1];
    int k = s;
    for (; k + 8 <= e; k += 8) {
        unsigned int w[8];
        #pragma unroll
        for (int j = 0; j < 8; ++j) {
            const unsigned char* p = X8 + (size_t)col[k + j] * D + boff;
            w[j] = (BPL == 4) ? *reinterpret_cast<const unsigned int*>(p)
                              : (unsigned int)*reinterpret_cast<const unsigned short*>(p);
        }
        #pragma unroll
        for (int j = 0; j < 8; ++j) {
            f32x2 lo = __builtin_amdgcn_cvt_pk_f32_fp8(w[j], false);
            a0 += lo.x; a1 += lo.y;
            if constexpr (BPL == 4) {
                f32x2 hi = __builtin_amdgcn_cvt_pk_f32_fp8(w[j], true);
                a2 += hi.x; a3 += hi.y;
            }
        }
    }
    for (; k < e; ++k) {
        const unsigned char* p = X8 + (size_t)col[k] * D + boff;
        unsigned int w = (BPL == 4) ? *reinterpret_cast<const unsigned int*>(p)
                                    : (unsigned int)*reinterpret_cast<const unsigned short*>(p);
        f32x2 lo = __builtin_amdgcn_cvt_pk_f32_fp8(w, false);
        a0 += lo.x; a1 += lo.y;
        if constexpr (BPL == 4) {
            f32x2 hi = __builtin_amdgcn_cvt_pk_f32_fp8(w, true);
            a2 += hi.x; a3 += hi.y;
        }
    }
    unsigned short* op = (unsigned short*)out + (size_t)node * D + boff;
    if constexpr (BPL == 4) {
        ushort4 o;
        o.x = f2bf(a0); o.y = f2bf(a1); o.z = f2bf(a2); o.w = f2bf(a3);
        *reinterpret_cast<ushort4*>(op) = o;
    } else {
        ushort2 o;
        o.x = f2bf(a0); o.y = f2bf(a1);
        *reinterpret_cast<ushort2*>(op) = o;
    }
}

// ---------------------------------------------------------------------------
// fused per-layer MLP: out = relu(relu(A @ W1t^T + b1) @ W2t^T + b2)
// BM=64, BN=256; 4 waves; plain-__syncthreads double-buffered gload_lds staging.
// FP8OUT=1 -> write fp8 e4m3 to C8; else bf16 to C.
template<int K1, int FP8OUT>
__global__ __launch_bounds__(256) void gin_mlp(
    const __hip_bfloat16* __restrict__ A, const __hip_bfloat16* __restrict__ W1t,
    const float* __restrict__ b1, const __hip_bfloat16* __restrict__ W2t,
    const float* __restrict__ b2, __hip_bfloat16* __restrict__ C,
    unsigned char* __restrict__ C8)
{
    __shared__ int4 smem4[4608];       // 73728 B
    char* smem = (char*)smem4;
    char* mid = smem + 40960;          // 64 x 512B

    int tid = threadIdx.x;
    int lane = tid & 63;
    int wid = tid >> 6;                // wave -> col slice
    int m0 = blockIdx.x * 64;

    int r16 = lane & 15;
    int g = lane >> 4;
    int gg = g ^ ((r16 >> 1) & 3);     // read-side chunk swizzle (64B-row tiles)

    int rseg = lane >> 2;
    int sw = (lane & 3) ^ ((lane >> 3) & 3);
    int rA = wid * 16 + rseg;

    const char* gA = (const char*)A + (size_t)(m0 + rA) * (K1 * 2) + sw * 16;
    const char* gW1[4];
    #pragma unroll
    for (int j = 0; j < 4; ++j) {
        int rW = (wid + 4 * j) * 16 + rseg;
        gW1[j] = (const char*)W1t + (size_t)rW * (K1 * 2) + sw * 16;
    }

    auto stage1 = [&](int buf, int t) {
        char* l = smem + buf * 20480;
        gl16(gA + t * 64, l + wid * 1024);
        #pragma unroll
        for (int j = 0; j < 4; ++j)
            gl16(gW1[j] + t * 64, l + 4096 + (wid + 4 * j) * 1024);
    };

    // ---- stage 1 ----
    f32x4 acc[4][4] = {};
    constexpr int NT1 = K1 / 32;

    stage1(0, 0);
    __syncthreads();
    #pragma unroll
    for (int t = 0; t < NT1; ++t) {
        int cur = t & 1;
        if (t + 1 < NT1) stage1(cur ^ 1, t + 1);
        const char* As = smem + cur * 20480;
        const char* Bs = As + 4096;
        bf16x8 af[4], bfv[4];
        #pragma unroll
        for (int m = 0; m < 4; ++m)
            af[m] = *reinterpret_cast<const bf16x8*>(As + (m * 16 + r16) * 64 + gg * 16);
        #pragma unroll
        for (int n = 0; n < 4; ++n)
            bfv[n] = *reinterpret_cast<const bf16x8*>(Bs + (wid * 64 + n * 16 + r16) * 64 + gg * 16);
        #pragma unroll
        for (int m = 0; m < 4; ++m)
            #pragma unroll
            for (int n = 0; n < 4; ++n)
                acc[m][n] = __builtin_amdgcn_mfma_f32_16x16x32_bf16(af[m], bfv[n], acc[m][n], 0, 0, 0);
        __syncthreads();
    }

    // issue W2 tile 0 early
    const char* gW2[4];
    #pragma unroll
    for (int j = 0; j < 4; ++j) {
        int rW = (wid + 4 * j) * 16 + rseg;
        gW2[j] = (const char*)W2t + (size_t)rW * 512 + sw * 16;
    }
    auto stageW2 = [&](int buf, int t) {
        char* l = smem + buf * 16384;
        #pragma unroll
        for (int j = 0; j < 4; ++j)
            gl16(gW2[j] + t * 64, l + (wid + 4 * j) * 1024);
    };
    stageW2(0, 0);

    // epilogue 1: bias+relu -> bf16 -> mid (swizzled). C/D: col=lane&15, row=g*4+reg
    #pragma unroll
    for (int m = 0; m < 4; ++m) {
        #pragma unroll
        for (int n = 0; n < 4; ++n) {
            int colX = wid * 64 + n * 16 + r16;
            float bb = b1[colX];
            int cb = colX >> 3;
            int within = (colX & 7) * 2;
            #pragma unroll
            for (int r = 0; r < 4; ++r) {
                int row = m * 16 + g * 4 + r;
                float v = fmaxf(acc[m][n][r] + bb, 0.f);
                *reinterpret_cast<unsigned short*>(
                    mid + row * 512 + ((cb ^ (row & 7)) << 4) + within) = f2bf(v);
            }
        }
    }

    __syncthreads();   // W2 tile0 ready, mid visible

    // ---- stage 2 ----
    f32x4 acc2[4][4] = {};
    #pragma unroll
    for (int t = 0; t < 8; ++t) {
        int cur = t & 1;
        if (t + 1 < 8) stageW2(cur ^ 1, t + 1);
        const char* Bs = smem + cur * 16384;
        bf16x8 af[4], bfv[4];
        #pragma unroll
        for (int m = 0; m < 4; ++m) {
            int row = m * 16 + r16;
            int c = (t * 4 + g) ^ (row & 7);
            af[m] = *reinterpret_cast<const bf16x8*>(mid + row * 512 + c * 16);
        }
        #pragma unroll
        for (int n = 0; n < 4; ++n)
            bfv[n] = *reinterpret_cast<const bf16x8*>(Bs + (wid * 64 + n * 16 + r16) * 64 + gg * 16);
        #pragma unroll
        for (int m = 0; m < 4; ++m)
            #pragma unroll
            for (int n = 0; n < 4; ++n)
                acc2[m][n] = __builtin_amdgcn_mfma_f32_16x16x32_bf16(af[m], bfv[n], acc2[m][n], 0, 0, 0);
        __syncthreads();
    }

    // epilogue 2: bias+relu -> fp8 or bf16
    #pragma unroll
    for (int m = 0; m < 4; ++m) {
        #pragma unroll
        for (int n = 0; n < 4; ++n) {
            int colX = wid * 64 + n * 16 + r16;
            float bb = b2[colX];
            #pragma unroll
            for (int r = 0; r < 4; ++r) {
                int row = m0 + m * 16 + g * 4 + r;
                float v = fmaxf(acc2[m][n][r] + bb, 0.f);
                if constexpr (FP8OUT) {
                    int b = __builtin_amdgcn_cvt_pk_fp8_f32(v, 0.f, 0, false);
                    C8[(size_t)row * HID + colX] = (unsigned char)(b & 0xff);
                } else {
                    C[(size_t)row * HID + colX] = __float2bfloat16(v);
                }
            }
        }
    }
}

// ---------------------------------------------------------------------------
// pooling: per-block register acc over 128 sorted nodes, atomic flush at
// graph boundaries. pooled zeroed by zero_int.
__global__ __launch_bounds__(256) void pool_partial(
    const __hip_bfloat16* __restrict__ h, const int* __restrict__ batch,
    float* __restrict__ pooled)
{
    __shared__ int sb[128];
    int n0 = blockIdx.x * 128;
    int cnt = N_NODES - n0; if (cnt > 128) cnt = 128;
    int d = threadIdx.x;
    if (d < cnt) sb[d] = batch[n0 + d];
    __syncthreads();
    float acc = 0.f;
    int cur = sb[0];
    for (int i = 0; i < cnt; ++i) {
        int g = sb[i];
        if (g != cur) { atomicAdd(&pooled[cur * HID + d], acc); acc = 0.f; cur = g; }
        acc += bf2f(*reinterpret_cast<const unsigned short*>(h + (size_t)(n0 + i) * HID + d));
    }
    atomicAdd(&pooled[cur * HID + d], acc);
}

// head: logits = pooled @ wl + bl ; log_softmax
__global__ __launch_bounds__(256) void head_kernel(
    const float* __restrict__ pooled, const float* __restrict__ wl,
    const float* __restrict__ bl, float* __restrict__ out)
{
    int gph = blockIdx.x;
    int d = threadIdx.x;
    __shared__ float p[HID];
    __shared__ float logits[OUT_DIM];
    __shared__ float lse_s;
    p[d] = pooled[gph * HID + d];
    __syncthreads();
    if (d < OUT_DIM) {
        float v = bl[d];
        for (int k = 0; k < HID; ++k) v += p[k] * wl[k * OUT_DIM + d];
        logits[d] = v;
    }
    __syncthreads();
    if (d == 0) {
        float mx = logits[0];
        for (int j = 1; j < OUT_DIM; ++j) mx = fmaxf(mx, logits[j]);
        float s = 0.f;
        for (int j = 0; j < OUT_DIM; ++j) s += expf(logits[j] - mx);
        lse_s = mx + logf(s);
    }
    __syncthreads();
    if (d < OUT_DIM) out[gph * OUT_DIM + d] = logits[d] - lse_s;
}

// ---------------------------------------------------------------------------
extern "C" void kernel_launch(void* const* d_in, const int* in_sizes, int n_in,
                              void* d_out, int out_size, void* d_ws, size_t ws_size,
                              hipStream_t stream) {
    const float* x    = (const float*)d_in[0];
    const int*   ei   = (const int*)d_in[1];
    const int*   batch= (const int*)d_in[2];
    const float* w1a  = (const float*)d_in[3];
    const float* b1a  = (const float*)d_in[4];
    const float* w1b  = (const float*)d_in[5];
    const float* b1b  = (const float*)d_in[6];
    const float* w2a  = (const float*)d_in[7];
    const float* b2a  = (const float*)d_in[8];
    const float* w2b  = (const float*)d_in[9];
    const float* b2b  = (const float*)d_in[10];
    const float* w3a  = (const float*)d_in[11];
    const float* b3a  = (const float*)d_in[12];
    const float* w3b  = (const float*)d_in[13];
    const float* b3b  = (const float*)d_in[14];
    const float* wl   = (const float*)d_in[15];
    const float* bl   = (const float*)d_in[16];

    const int* src = ei;
    const int* dst = ei + N_EDGES;

    __hip_bfloat16* bufA = (__hip_bfloat16*)d_ws;                  // M_PAD*256 bf16
    __hip_bfloat16* bufB = bufA + (size_t)M_PAD * HID;             // M_PAD*256 bf16
    unsigned char*  h8   = (unsigned char*)(bufB + (size_t)M_PAD * HID); // M_PAD*256 fp8
    unsigned char*  x_f8 = h8 + (size_t)M_PAD * HID;               // N_NODES*128 fp8
    __hip_bfloat16* wt1a = (__hip_bfloat16*)(x_f8 + (size_t)N_NODES * IN_DIM);
    __hip_bfloat16* wt1b = wt1a + HID * IN_DIM;                    // 256*256
    __hip_bfloat16* wt2a = wt1b + HID * HID;
    __hip_bfloat16* wt2b = wt2a + HID * HID;
    __hip_bfloat16* wt3a = wt2b + HID * HID;
    __hip_bfloat16* wt3b = wt3a + HID * HID;
    float* pooled = (float*)(wt3b + HID * HID);                    // 64*256
    int* deg     = (int*)(pooled + N_GRAPHS * HID);                // contiguous w/ pooled
    int* row_ptr = deg + N_NODES;
    int* pos     = row_ptr + (N_NODES + 1);
    int* col     = pos + N_NODES;                                  // N_EDGES

    float* out = (float*)d_out;

    // ---- prep: zero pooled+deg (own kernel, NOT hipMemsetAsync), then fused
    //      transpose/x-fp8/hist ----
    int zn = N_GRAPHS * HID + N_NODES;
    zero_int<<<(zn + 255) / 256, 256, 0, stream>>>((int*)pooled, zn);

    int n4 = N_NODES * IN_DIM / 4;
    transpose_all<<<dim3(8, 8, 8), 256, 0, stream>>>(
        w1a, w1b, w2a, w2b, w3a, w3b, wt1a, wt1b, wt2a, wt2b, wt3a, wt3b,
        x, x_f8, n4, dst, deg);

    scan_deg<<<1, 1024, 0, stream>>>(deg, row_ptr, pos, N_NODES);
    csr_fill<<<(N_EDGES + 255) / 256, 256, 0, stream>>>(src, dst, pos, col, N_EDGES);

    int agg_blocks = (N_NODES + 3) / 4;
    int mlp_blocks = M_PAD / 64;

    // ---- layer 1: fp8 gather, MLP -> fp8 h ----
    gin_agg_f8<IN_DIM><<<agg_blocks, 256, 0, stream>>>(x_f8, row_ptr, col, bufA);
    gin_mlp<IN_DIM, 1><<<mlp_blocks, 256, 0, stream>>>(bufA, wt1a, b1a, wt1b, b1b, bufB, h8);

    // ---- layer 2: fp8 gather, MLP -> fp8 h ----
    gin_agg_f8<HID><<<agg_blocks, 256, 0, stream>>>(h8, row_ptr, col, bufA);
    gin_mlp<HID, 1><<<mlp_blocks, 256, 0, stream>>>(bufA, wt2a, b2a, wt2b, b2b, bufB, h8);

    // ---- layer 3: fp8 gather, MLP -> bf16 h ----
    gin_agg_f8<HID><<<agg_blocks, 256, 0, stream>>>(h8, row_ptr, col, bufA);
    gin_mlp<HID, 0><<<mlp_blocks, 256, 0, stream>>>(bufA, wt3a, b3a, wt3b, b3b, bufB, h8);

    // ---- pool + head ----
    pool_partial<<<(N_NODES + 127) / 128, 256, 0, stream>>>(bufB, batch, pooled);
    head_kernel<<<N_GRAPHS, 256, 0, stream>>>(pooled, wl, bl, out);
}

// Round 12
// 188.245 us; speedup vs baseline: 1.8564x; 1.1685x over previous
//
#include <hip/hip_runtime.h>
#include <hip/hip_bf16.h>

#define N_NODES 20000
#define M_PAD 20096            // 314 * 64
#define IN_DIM 128
#define HID 256
#define OUT_DIM 10
#define N_EDGES 320000
#define N_GRAPHS 64

typedef __attribute__((ext_vector_type(8))) short bf16x8;
typedef __attribute__((ext_vector_type(4))) float f32x4;
typedef __attribute__((ext_vector_type(2))) float f32x2;

__device__ inline float bf2f(unsigned short u) {
    return __uint_as_float((unsigned int)u << 16);
}
__device__ inline unsigned short f2bf(float f) {
    __hip_bfloat16 h = __float2bfloat16(f);
    return *reinterpret_cast<unsigned short*>(&h);
}

__device__ __forceinline__ void gl16(const void* g, void* l) {
    __builtin_amdgcn_global_load_lds(
        (const __attribute__((address_space(1))) unsigned int*)g,
        (__attribute__((address_space(3))) unsigned int*)l, 16, 0, 0);
}

// ---------------------------------------------------------------------------
__global__ void zero_int(int* __restrict__ p, int n) {
    int i = blockIdx.x * blockDim.x + threadIdx.x;
    if (i < n) p[i] = 0;
}

// ---------------------------------------------------------------------------
// CSR build (deg zeroed by zero_int; histogram fused into transpose_all)
__global__ __launch_bounds__(1024) void scan_deg(const int* __restrict__ deg,
                                                 int* __restrict__ row_ptr,
                                                 int* __restrict__ pos, int n) {
    __shared__ int sums[1024];
    int tid = threadIdx.x;
    int chunk = (n + 1023) / 1024;
    int base = tid * chunk;
    int s = 0;
    for (int i = 0; i < chunk; ++i) {
        int idx = base + i;
        if (idx < n) s += deg[idx];
    }
    sums[tid] = s;
    __syncthreads();
    for (int off = 1; off < 1024; off <<= 1) {
        int v = (tid >= off) ? sums[tid - off] : 0;
        __syncthreads();
        if (tid >= off) sums[tid] += v;
        __syncthreads();
    }
    int run = (tid == 0) ? 0 : sums[tid - 1];
    for (int i = 0; i < chunk; ++i) {
        int idx = base + i;
        if (idx < n) {
            row_ptr[idx] = run;
            pos[idx] = run;
            run += deg[idx];
            if (idx == n - 1) row_ptr[n] = run;
        }
    }
}

__global__ void csr_fill(const int* __restrict__ src, const int* __restrict__ dst,
                         int* __restrict__ pos, int* __restrict__ col, int n) {
    int i = blockIdx.x * blockDim.x + threadIdx.x;
    int stride = gridDim.x * blockDim.x;
    for (; i < n; i += stride) {
        int slot = atomicAdd(&pos[dst[i]], 1);
        col[slot] = src[i];
    }
}

// ---------------------------------------------------------------------------
// batched prep: z<6 weight transpose+convert; z==6 x->fp8; z==7 degree_hist
__global__ __launch_bounds__(256) void transpose_all(
    const float* __restrict__ w1a, const float* __restrict__ w1b,
    const float* __restrict__ w2a, const float* __restrict__ w2b,
    const float* __restrict__ w3a, const float* __restrict__ w3b,
    __hip_bfloat16* __restrict__ o1a, __hip_bfloat16* __restrict__ o1b,
    __hip_bfloat16* __restrict__ o2a, __hip_bfloat16* __restrict__ o2b,
    __hip_bfloat16* __restrict__ o3a, __hip_bfloat16* __restrict__ o3b,
    const float* __restrict__ x, unsigned char* __restrict__ x_f8, int n4,
    const int* __restrict__ dst, int* __restrict__ deg)
{
    __shared__ float tile[32][33];
    int z = blockIdx.z;
    if (z == 6) {
        int i = (blockIdx.y * 8 + blockIdx.x) * 256 + threadIdx.x;
        for (; i < n4; i += 64 * 256) {
            float4 v = reinterpret_cast<const float4*>(x)[i];
            int w = __builtin_amdgcn_cvt_pk_fp8_f32(v.x, v.y, 0, false);
            w = __builtin_amdgcn_cvt_pk_fp8_f32(v.z, v.w, w, true);
            reinterpret_cast<unsigned int*>(x_f8)[i] = (unsigned int)w;
        }
        return;
    }
    if (z == 7) {
        int i = (blockIdx.y * 8 + blockIdx.x) * 256 + threadIdx.x;
        for (; i < N_EDGES; i += 64 * 256) atomicAdd(&deg[dst[i]], 1);
        return;
    }
    const float* in = (z == 0) ? w1a : (z == 1) ? w1b : (z == 2) ? w2a
                    : (z == 3) ? w2b : (z == 4) ? w3a : w3b;
    __hip_bfloat16* out = (z == 0) ? o1a : (z == 1) ? o1b : (z == 2) ? o2a
                        : (z == 3) ? o2b : (z == 4) ? o3a : o3b;
    int rows = (z == 0) ? IN_DIM : HID;
    int r0 = blockIdx.y * 32;
    if (r0 >= rows) return;
    int c0 = blockIdx.x * 32;
    int tx = threadIdx.x & 31, ty = threadIdx.x >> 5;
    for (int i = ty; i < 32; i += 8)
        tile[i][tx] = in[(size_t)(r0 + i) * HID + c0 + tx];
    __syncthreads();
    for (int i = ty; i < 32; i += 8)
        out[(size_t)(c0 + i) * rows + r0 + tx] = __float2bfloat16(tile[tx][i]);
}

// ---------------------------------------------------------------------------
// fp8 gather-aggregate: out_bf16[i] = x[i] + sum_{j in in-edges(i)} x[j]
// one wave per node; tiered 16/8/1 unroll (mean degree = 16 -> one load round).
template<int D>
__global__ __launch_bounds__(256) void gin_agg_f8(
    const unsigned char* __restrict__ X8, const int* __restrict__ row_ptr,
    const int* __restrict__ col, __hip_bfloat16* __restrict__ out)
{
    int node = blockIdx.x * 4 + (threadIdx.x >> 6);
    if (node >= N_NODES) return;
    int lane = threadIdx.x & 63;
    constexpr int BPL = D / 64;        // bytes (=dims) per lane: 4 or 2
    int boff = lane * BPL;

    float a0 = 0.f, a1 = 0.f, a2 = 0.f, a3 = 0.f;
    {
        const unsigned char* p = X8 + (size_t)node * D + boff;
        unsigned int w = (BPL == 4) ? *reinterpret_cast<const unsigned int*>(p)
                                    : (unsigned int)*reinterpret_cast<const unsigned short*>(p);
        f32x2 lo = __builtin_amdgcn_cvt_pk_f32_fp8(w, false);
        a0 = lo.x; a1 = lo.y;
        if constexpr (BPL == 4) {
            f32x2 hi = __builtin_amdgcn_cvt_pk_f32_fp8(w, true);
            a2 = hi.x; a3 = hi.y;
        }
    }
    int s = row_ptr[node], e = row_ptr[node + 1];
    int k = s;
    for (; k + 16 <= e; k += 16) {
        unsigned int w[16];
        #pragma unroll
        for (int j = 0; j < 16; ++j) {
            const unsigned char* p = X8 + (size_t)col[k + j] * D + boff;
            w[j] = (BPL == 4) ? *reinterpret_cast<const unsigned int*>(p)
                              : (unsigned int)*reinterpret_cast<const unsigned short*>(p);
        }
        #pragma unroll
        for (int j = 0; j < 16; ++j) {
            f32x2 lo = __builtin_amdgcn_cvt_pk_f32_fp8(w[j], false);
            a0 += lo.x; a1 += lo.y;
            if constexpr (BPL == 4) {
                f32x2 hi = __builtin_amdgcn_cvt_pk_f32_fp8(w[j], true);
                a2 += hi.x; a3 += hi.y;
            }
        }
    }
    if (k + 8 <= e) {
        unsigned int w[8];
        #pragma unroll
        for (int j = 0; j < 8; ++j) {
            const unsigned char* p = X8 + (size_t)col[k + j] * D + boff;
            w[j] = (BPL == 4) ? *reinterpret_cast<const unsigned int*>(p)
                              : (unsigned int)*reinterpret_cast<const unsigned short*>(p);
        }
        #pragma unroll
        for (int j = 0; j < 8; ++j) {
            f32x2 lo = __builtin_amdgcn_cvt_pk_f32_fp8(w[j], false);
            a0 += lo.x; a1 += lo.y;
            if constexpr (BPL == 4) {
                f32x2 hi = __builtin_amdgcn_cvt_pk_f32_fp8(w[j], true);
                a2 += hi.x; a3 += hi.y;
            }
        }
        k += 8;
    }
    for (; k < e; ++k) {
        const unsigned char* p = X8 + (size_t)col[k] * D + boff;
        unsigned int w = (BPL == 4) ? *reinterpret_cast<const unsigned int*>(p)
                                    : (unsigned int)*reinterpret_cast<const unsigned short*>(p);
        f32x2 lo = __builtin_amdgcn_cvt_pk_f32_fp8(w, false);
        a0 += lo.x; a1 += lo.y;
        if constexpr (BPL == 4) {
            f32x2 hi = __builtin_amdgcn_cvt_pk_f32_fp8(w, true);
            a2 += hi.x; a3 += hi.y;
        }
    }
    unsigned short* op = (unsigned short*)out + (size_t)node * D + boff;
    if constexpr (BPL == 4) {
        ushort4 o;
        o.x = f2bf(a0); o.y = f2bf(a1); o.z = f2bf(a2); o.w = f2bf(a3);
        *reinterpret_cast<ushort4*>(op) = o;
    } else {
        ushort2 o;
        o.x = f2bf(a0); o.y = f2bf(a1);
        *reinterpret_cast<ushort2*>(op) = o;
    }
}

// ---------------------------------------------------------------------------
// fused per-layer MLP: h = relu(relu(A @ W1t^T + b1) @ W2t^T + b2)
// BM=64, BN=256; 4 waves; double-buffered gload_lds staging.
// MODE 0: h -> bf16 C.  MODE 1: h -> fp8 C8.  MODE 2: h -> LDS, then fused
// segment-pooling (batch sorted) with atomic flush into pooled.
template<int K1, int MODE>
__global__ __launch_bounds__(256) void gin_mlp(
    const __hip_bfloat16* __restrict__ A, const __hip_bfloat16* __restrict__ W1t,
    const float* __restrict__ b1, const __hip_bfloat16* __restrict__ W2t,
    const float* __restrict__ b2, __hip_bfloat16* __restrict__ C,
    unsigned char* __restrict__ C8,
    const int* __restrict__ batch, float* __restrict__ pooled)
{
    __shared__ int4 smem4[4672];       // 74752 B (72K stage/mid + 1K batch pad)
    char* smem = (char*)smem4;
    char* mid = smem + 40960;          // 64 x 512B
    int* sbatch = (int*)(smem + 73728);

    int tid = threadIdx.x;
    int lane = tid & 63;
    int wid = tid >> 6;                // wave -> col slice
    int m0 = blockIdx.x * 64;

    int r16 = lane & 15;
    int g = lane >> 4;
    int gg = g ^ ((r16 >> 1) & 3);     // read-side chunk swizzle (64B-row tiles)

    int rseg = lane >> 2;
    int sw = (lane & 3) ^ ((lane >> 3) & 3);
    int rA = wid * 16 + rseg;

    const char* gA = (const char*)A + (size_t)(m0 + rA) * (K1 * 2) + sw * 16;
    const char* gW1[4];
    #pragma unroll
    for (int j = 0; j < 4; ++j) {
        int rW = (wid + 4 * j) * 16 + rseg;
        gW1[j] = (const char*)W1t + (size_t)rW * (K1 * 2) + sw * 16;
    }

    auto stage1 = [&](int buf, int t) {
        char* l = smem + buf * 20480;
        gl16(gA + t * 64, l + wid * 1024);
        #pragma unroll
        for (int j = 0; j < 4; ++j)
            gl16(gW1[j] + t * 64, l + 4096 + (wid + 4 * j) * 1024);
    };

    // ---- stage 1 ----
    f32x4 acc[4][4] = {};
    constexpr int NT1 = K1 / 32;

    stage1(0, 0);
    __syncthreads();
    #pragma unroll
    for (int t = 0; t < NT1; ++t) {
        int cur = t & 1;
        if (t + 1 < NT1) stage1(cur ^ 1, t + 1);
        const char* As = smem + cur * 20480;
        const char* Bs = As + 4096;
        bf16x8 af[4], bfv[4];
        #pragma unroll
        for (int m = 0; m < 4; ++m)
            af[m] = *reinterpret_cast<const bf16x8*>(As + (m * 16 + r16) * 64 + gg * 16);
        #pragma unroll
        for (int n = 0; n < 4; ++n)
            bfv[n] = *reinterpret_cast<const bf16x8*>(Bs + (wid * 64 + n * 16 + r16) * 64 + gg * 16);
        #pragma unroll
        for (int m = 0; m < 4; ++m)
            #pragma unroll
            for (int n = 0; n < 4; ++n)
                acc[m][n] = __builtin_amdgcn_mfma_f32_16x16x32_bf16(af[m], bfv[n], acc[m][n], 0, 0, 0);
        __syncthreads();
    }

    // issue W2 tile 0 early
    const char* gW2[4];
    #pragma unroll
    for (int j = 0; j < 4; ++j) {
        int rW = (wid + 4 * j) * 16 + rseg;
        gW2[j] = (const char*)W2t + (size_t)rW * 512 + sw * 16;
    }
    auto stageW2 = [&](int buf, int t) {
        char* l = smem + buf * 16384;
        #pragma unroll
        for (int j = 0; j < 4; ++j)
            gl16(gW2[j] + t * 64, l + (wid + 4 * j) * 1024);
    };
    stageW2(0, 0);

    // epilogue 1: bias+relu -> bf16 -> mid (swizzled). C/D: col=lane&15, row=g*4+reg
    #pragma unroll
    for (int m = 0; m < 4; ++m) {
        #pragma unroll
        for (int n = 0; n < 4; ++n) {
            int colX = wid * 64 + n * 16 + r16;
            float bb = b1[colX];
            int cb = colX >> 3;
            int within = (colX & 7) * 2;
            #pragma unroll
            for (int r = 0; r < 4; ++r) {
                int row = m * 16 + g * 4 + r;
                float v = fmaxf(acc[m][n][r] + bb, 0.f);
                *reinterpret_cast<unsigned short*>(
                    mid + row * 512 + ((cb ^ (row & 7)) << 4) + within) = f2bf(v);
            }
        }
    }

    __syncthreads();   // W2 tile0 ready, mid visible

    // ---- stage 2 ----
    f32x4 acc2[4][4] = {};
    #pragma unroll
    for (int t = 0; t < 8; ++t) {
        int cur = t & 1;
        if (t + 1 < 8) stageW2(cur ^ 1, t + 1);
        const char* Bs = smem + cur * 16384;
        bf16x8 af[4], bfv[4];
        #pragma unroll
        for (int m = 0; m < 4; ++m) {
            int row = m * 16 + r16;
            int c = (t * 4 + g) ^ (row & 7);
            af[m] = *reinterpret_cast<const bf16x8*>(mid + row * 512 + c * 16);
        }
        #pragma unroll
        for (int n = 0; n < 4; ++n)
            bfv[n] = *reinterpret_cast<const bf16x8*>(Bs + (wid * 64 + n * 16 + r16) * 64 + gg * 16);
        #pragma unroll
        for (int m = 0; m < 4; ++m)
            #pragma unroll
            for (int n = 0; n < 4; ++n)
                acc2[m][n] = __builtin_amdgcn_mfma_f32_16x16x32_bf16(af[m], bfv[n], acc2[m][n], 0, 0, 0);
        __syncthreads();
    }

    // epilogue 2
    if constexpr (MODE == 2) {
        // write h tile to mid (plain [row][col] layout) + stage batch ids
        #pragma unroll
        for (int m = 0; m < 4; ++m) {
            #pragma unroll
            for (int n = 0; n < 4; ++n) {
                int colX = wid * 64 + n * 16 + r16;
                float bb = b2[colX];
                #pragma unroll
                for (int r = 0; r < 4; ++r) {
                    int row = m * 16 + g * 4 + r;
                    float v = fmaxf(acc2[m][n][r] + bb, 0.f);
                    *reinterpret_cast<unsigned short*>(mid + row * 512 + colX * 2) = f2bf(v);
                }
            }
        }
        int rlim = N_NODES - m0;
        if (rlim > 64) rlim = 64;
        if (tid < 64 && tid < rlim) sbatch[tid] = batch[m0 + tid];
        __syncthreads();
        if (rlim > 0) {
            int colp = tid;                 // 0..255
            float pacc = 0.f;
            int cur = sbatch[0];
            for (int i = 0; i < rlim; ++i) {
                int gph = sbatch[i];
                if (gph != cur) { atomicAdd(&pooled[cur * HID + colp], pacc); pacc = 0.f; cur = gph; }
                pacc += bf2f(*reinterpret_cast<unsigned short*>(mid + i * 512 + colp * 2));
            }
            atomicAdd(&pooled[cur * HID + colp], pacc);
        }
    } else {
        #pragma unroll
        for (int m = 0; m < 4; ++m) {
            #pragma unroll
            for (int n = 0; n < 4; ++n) {
                int colX = wid * 64 + n * 16 + r16;
                float bb = b2[colX];
                #pragma unroll
                for (int r = 0; r < 4; ++r) {
                    int row = m0 + m * 16 + g * 4 + r;
                    float v = fmaxf(acc2[m][n][r] + bb, 0.f);
                    if constexpr (MODE == 1) {
                        int b = __builtin_amdgcn_cvt_pk_fp8_f32(v, 0.f, 0, false);
                        C8[(size_t)row * HID + colX] = (unsigned char)(b & 0xff);
                    } else {
                        C[(size_t)row * HID + colX] = __float2bfloat16(v);
                    }
                }
            }
        }
    }
}

// head: logits = pooled @ wl + bl ; log_softmax
__global__ __launch_bounds__(256) void head_kernel(
    const float* __restrict__ pooled, const float* __restrict__ wl,
    const float* __restrict__ bl, float* __restrict__ out)
{
    int gph = blockIdx.x;
    int d = threadIdx.x;
    __shared__ float p[HID];
    __shared__ float logits[OUT_DIM];
    __shared__ float lse_s;
    p[d] = pooled[gph * HID + d];
    __syncthreads();
    if (d < OUT_DIM) {
        float v = bl[d];
        for (int k = 0; k < HID; ++k) v += p[k] * wl[k * OUT_DIM + d];
        logits[d] = v;
    }
    __syncthreads();
    if (d == 0) {
        float mx = logits[0];
        for (int j = 1; j < OUT_DIM; ++j) mx = fmaxf(mx, logits[j]);
        float s = 0.f;
        for (int j = 0; j < OUT_DIM; ++j) s += expf(logits[j] - mx);
        lse_s = mx + logf(s);
    }
    __syncthreads();
    if (d < OUT_DIM) out[gph * OUT_DIM + d] = logits[d] - lse_s;
}

// ---------------------------------------------------------------------------
extern "C" void kernel_launch(void* const* d_in, const int* in_sizes, int n_in,
                              void* d_out, int out_size, void* d_ws, size_t ws_size,
                              hipStream_t stream) {
    const float* x    = (const float*)d_in[0];
    const int*   ei   = (const int*)d_in[1];
    const int*   batch= (const int*)d_in[2];
    const float* w1a  = (const float*)d_in[3];
    const float* b1a  = (const float*)d_in[4];
    const float* w1b  = (const float*)d_in[5];
    const float* b1b  = (const float*)d_in[6];
    const float* w2a  = (const float*)d_in[7];
    const float* b2a  = (const float*)d_in[8];
    const float* w2b  = (const float*)d_in[9];
    const float* b2b  = (const float*)d_in[10];
    const float* w3a  = (const float*)d_in[11];
    const float* b3a  = (const float*)d_in[12];
    const float* w3b  = (const float*)d_in[13];
    const float* b3b  = (const float*)d_in[14];
    const float* wl   = (const float*)d_in[15];
    const float* bl   = (const float*)d_in[16];

    const int* src = ei;
    const int* dst = ei + N_EDGES;

    __hip_bfloat16* bufA = (__hip_bfloat16*)d_ws;                  // M_PAD*256 bf16
    __hip_bfloat16* bufB = bufA + (size_t)M_PAD * HID;             // M_PAD*256 bf16
    unsigned char*  h8   = (unsigned char*)(bufB + (size_t)M_PAD * HID); // M_PAD*256 fp8
    unsigned char*  x_f8 = h8 + (size_t)M_PAD * HID;               // N_NODES*128 fp8
    __hip_bfloat16* wt1a = (__hip_bfloat16*)(x_f8 + (size_t)N_NODES * IN_DIM);
    __hip_bfloat16* wt1b = wt1a + HID * IN_DIM;                    // 256*256
    __hip_bfloat16* wt2a = wt1b + HID * HID;
    __hip_bfloat16* wt2b = wt2a + HID * HID;
    __hip_bfloat16* wt3a = wt2b + HID * HID;
    __hip_bfloat16* wt3b = wt3a + HID * HID;
    float* pooled = (float*)(wt3b + HID * HID);                    // 64*256
    int* deg     = (int*)(pooled + N_GRAPHS * HID);                // contiguous w/ pooled
    int* row_ptr = deg + N_NODES;
    int* pos     = row_ptr + (N_NODES + 1);
    int* col     = pos + N_NODES;                                  // N_EDGES

    float* out = (float*)d_out;

    // ---- prep: zero pooled+deg, then fused transpose/x-fp8/hist ----
    int zn = N_GRAPHS * HID + N_NODES;
    zero_int<<<(zn + 255) / 256, 256, 0, stream>>>((int*)pooled, zn);

    int n4 = N_NODES * IN_DIM / 4;
    transpose_all<<<dim3(8, 8, 8), 256, 0, stream>>>(
        w1a, w1b, w2a, w2b, w3a, w3b, wt1a, wt1b, wt2a, wt2b, wt3a, wt3b,
        x, x_f8, n4, dst, deg);

    scan_deg<<<1, 1024, 0, stream>>>(deg, row_ptr, pos, N_NODES);
    csr_fill<<<(N_EDGES + 255) / 256, 256, 0, stream>>>(src, dst, pos, col, N_EDGES);

    int agg_blocks = (N_NODES + 3) / 4;
    int mlp_blocks = M_PAD / 64;

    // ---- layer 1: fp8 gather, MLP -> fp8 h ----
    gin_agg_f8<IN_DIM><<<agg_blocks, 256, 0, stream>>>(x_f8, row_ptr, col, bufA);
    gin_mlp<IN_DIM, 1><<<mlp_blocks, 256, 0, stream>>>(bufA, wt1a, b1a, wt1b, b1b, bufB, h8, batch, pooled);

    // ---- layer 2: fp8 gather, MLP -> fp8 h ----
    gin_agg_f8<HID><<<agg_blocks, 256, 0, stream>>>(h8, row_ptr, col, bufA);
    gin_mlp<HID, 1><<<mlp_blocks, 256, 0, stream>>>(bufA, wt2a, b2a, wt2b, b2b, bufB, h8, batch, pooled);

    // ---- layer 3: fp8 gather, MLP -> fused pooling ----
    gin_agg_f8<HID><<<agg_blocks, 256, 0, stream>>>(h8, row_ptr, col, bufA);
    gin_mlp<HID, 2><<<mlp_blocks, 256, 0, stream>>>(bufA, wt3a, b3a, wt3b, b3b, bufB, h8, batch, pooled);

    // ---- head ----
    head_kernel<<<N_GRAPHS, 256, 0, stream>>>(pooled, wl, bl, out);
}